// Round 13
// baseline (522.432 us; speedup 1.0000x reference)
//
#include <hip/hip_runtime.h>
#include <hip/hip_fp16.h>
#include <math.h>

#define N   50000
#define E   800000
#define F   128
#define DIM 128
#define NF  4
#define ND  32
#define NL  3
#define NC  10
#define G   256
#define NB  196    // ceil(N/256) scan blocks

typedef __attribute__((ext_vector_type(8))) short  s16x8;   // 8 bf16 (4 VGPRs) MFMA operand
typedef __attribute__((ext_vector_type(4))) float  f32x4;   // MFMA accumulator

__device__ __forceinline__ float sigm(float v) { return 1.0f / (1.0f + __expf(-v)); }

__device__ __forceinline__ unsigned int f2bf(float x) {   // RNE round to bf16
    unsigned int u = __float_as_uint(x);
    return (u + 0x7FFFu + ((u >> 16) & 1u)) >> 16;
}

// split x into hi+lo bf16 pair (hi = bf16(x), lo = bf16(x - hi)): 3-term MFMA gives ~fp32
__device__ __forceinline__ void split8(const float* v, s16x8& hi, s16x8& lo) {
    #pragma unroll
    for (int i = 0; i < 8; ++i) {
        float x = v[i];
        unsigned int h = f2bf(x);
        float hf = __uint_as_float(h << 16);
        hi[i] = (short)h;
        lo[i] = (short)f2bf(x - hf);
    }
}

#define MFMA(a, b, c) c = __builtin_amdgcn_mfma_f32_16x16x32_bf16(a, b, c, 0, 0, 0)
// split product: (xh+xl)(wh+wl) ~= xh*wh + xh*wl + xl*wh
#define MF3(xh, xl, wh, wl, c) do { MFMA(xh, wh, c); MFMA(xh, wl, c); MFMA(xl, wh, c); } while (0)

// ---------------- one-shot setup: weight fragments + cc + goff ----------------
// blocks 0..11: conv frags (f*3+lay); 12..15: gru frags (f); 16..19: enc+att frags
// (vl/vr computed inline); 20: cc; 21: goff binary searches. 256 thr; frag blocks
// use lanes 0..63 only (one-shot kernel, waste is fine).
__global__ void setup_kernel(const float* __restrict__ lin0_W, const float* __restrict__ lin0_b,
                             const float* __restrict__ att_W, const float* __restrict__ att_b,
                             const float* __restrict__ Wrel, const float* __restrict__ Wroot,
                             const float* __restrict__ Wih, const float* __restrict__ Whh,
                             const float* __restrict__ enc_W, const int* __restrict__ batch,
                             unsigned short* __restrict__ convfrag,
                             unsigned short* __restrict__ grufrag,
                             unsigned short* __restrict__ encfrag,
                             unsigned short* __restrict__ attfrag,
                             float* __restrict__ cc, int* __restrict__ goff) {
    int b = blockIdx.x;
    int tid = threadIdx.x;
    if (b < 20 && tid >= 64) return;
    int l = tid & 63;
    int lr = l & 15, lg = l >> 4;
    if (b < 12) {
        const float* wrelg  = Wrel  + (size_t)b * 1024;   // b == f*NL+lay
        const float* wrootg = Wroot + (size_t)b * 1024;
        #pragma unroll
        for (int H = 0; H < 2; ++H) {
            #pragma unroll
            for (int i = 0; i < 8; ++i) {
                float x = wrelg[(lg * 8 + i) * 32 + H * 16 + lr];
                unsigned int h = f2bf(x);
                convfrag[(((size_t)b * 8 + 0 + H) * 64 + l) * 8 + i] = (unsigned short)h;
                convfrag[(((size_t)b * 8 + 2 + H) * 64 + l) * 8 + i] =
                    (unsigned short)f2bf(x - __uint_as_float(h << 16));
                x = wrootg[(lg * 8 + i) * 32 + H * 16 + lr];
                h = f2bf(x);
                convfrag[(((size_t)b * 8 + 4 + H) * 64 + l) * 8 + i] = (unsigned short)h;
                convfrag[(((size_t)b * 8 + 6 + H) * 64 + l) * 8 + i] =
                    (unsigned short)f2bf(x - __uint_as_float(h << 16));
            }
        }
    } else if (b < 16) {
        int f = b - 12;
        const float* wihg = Wih + (size_t)f * 3072;   // [96][32] row-major
        const float* whhg = Whh + (size_t)f * 3072;
        #pragma unroll
        for (int m = 0; m < 6; ++m) {
            const float* base = (m < 3 ? wihg : whhg) + (size_t)((m % 3) * 32) * 32;
            #pragma unroll
            for (int H = 0; H < 2; ++H) {
                int col = H * 16 + lr;
                #pragma unroll
                for (int i = 0; i < 8; ++i) {
                    float x = base[(size_t)col * 32 + lg * 8 + i];
                    unsigned int h = f2bf(x);
                    grufrag[(((size_t)(f * 6 + m) * 4 + H) * 64 + l) * 8 + i] = (unsigned short)h;
                    grufrag[(((size_t)(f * 6 + m) * 4 + 2 + H) * 64 + l) * 8 + i] =
                        (unsigned short)f2bf(x - __uint_as_float(h << 16));
                }
            }
        }
    } else if (b < 20) {
        int f = b - 16;
        const float* we = enc_W + (size_t)f * F * ND;   // [128][32]
        #pragma unroll
        for (int c = 0; c < 4; ++c) {
            #pragma unroll
            for (int i = 0; i < 8; ++i) {
                int k = c * 32 + lg * 8 + i;
                #pragma unroll
                for (int H = 0; H < 2; ++H) {
                    float x = we[(size_t)k * 32 + H * 16 + lr];
                    unsigned int h = f2bf(x);
                    encfrag[((((size_t)(f * 4 + c) * 2 + H) * 2 + 0) * 64 + l) * 8 + i] =
                        (unsigned short)h;
                    encfrag[((((size_t)(f * 4 + c) * 2 + H) * 2 + 1) * 64 + l) * 8 + i] =
                        (unsigned short)f2bf(x - __uint_as_float(h << 16));
                }
                float av = 0.f;
                if (lr < 2) {   // vl (lr==0) / vr (lr==1) computed inline
                    const float* W  = lin0_W + (size_t)f * F * DIM + (size_t)k * DIM;
                    const float* wv = att_W + f * 2 * DIM + lr * DIM;
                    for (int j = 0; j < DIM; ++j) av += W[j] * wv[j];
                }
                unsigned int ha = f2bf(av);
                attfrag[(((size_t)(f * 4 + c) * 2 + 0) * 64 + l) * 8 + i] = (unsigned short)ha;
                attfrag[(((size_t)(f * 4 + c) * 2 + 1) * 64 + l) * 8 + i] =
                    (unsigned short)f2bf(av - __uint_as_float(ha << 16));
            }
        }
    } else if (b == 20) {
        if (tid < NF) {
            const float* bb = lin0_b + tid * DIM;
            const float* wl = att_W + tid * 2 * DIM;
            const float* wr = wl + DIM;
            float s = att_b[tid];
            for (int j = 0; j < DIM; ++j) s += bb[j] * (wl[j] + wr[j]);
            cc[tid] = s;
        }
    } else {
        int g = tid;   // 0..255: goff[g] = lower_bound(batch, g)
        int lo = 0, hi = N;
        while (lo < hi) {
            int mid = (lo + hi) >> 1;
            if (batch[mid] < g) lo = mid + 1; else hi = mid;
        }
        goff[g] = lo;
        if (g == 0) goff[G] = N;
    }
}

// ---------------- encode via MFMA (split-bf16 ~= fp32) ----------------
__global__ __launch_bounds__(256) void encode_kernel(
        const float* __restrict__ x,
        const unsigned short* __restrict__ encfrag,
        const unsigned short* __restrict__ attfrag,
        const float* __restrict__ enc_b,
        float* __restrict__ out, unsigned short* __restrict__ st16,
        float* __restrict__ alr) {
    int tid = threadIdx.x;
    int f  = __builtin_amdgcn_readfirstlane(tid >> 6);
    int l  = tid & 63;
    int lr = l & 15, lg = l >> 4;
    int node0 = blockIdx.x * 32;

    s16x8 beh[4][2], bel[4][2], bah[4], bal[4];
    #pragma unroll
    for (int c = 0; c < 4; ++c) {
        #pragma unroll
        for (int H = 0; H < 2; ++H) {
            beh[c][H] = *(const s16x8*)&encfrag[((((size_t)(f*4 + c)*2 + H)*2 + 0)*64 + l)*8];
            bel[c][H] = *(const s16x8*)&encfrag[((((size_t)(f*4 + c)*2 + H)*2 + 1)*64 + l)*8];
        }
        bah[c] = *(const s16x8*)&attfrag[(((size_t)(f*4 + c)*2 + 0)*64 + l)*8];
        bal[c] = *(const s16x8*)&attfrag[(((size_t)(f*4 + c)*2 + 1)*64 + l)*8];
    }
    float be0 = enc_b[f*32 + lr], be1 = enc_b[f*32 + 16 + lr];

    #pragma unroll
    for (int s = 0; s < 2; ++s) {
        int n0 = node0 + s * 16;
        int na = n0 + lr; int nac = na < N ? na : N - 1;
        const float* px = x + (size_t)nac * F + lg * 8;
        s16x8 xh[4], xl[4];
        #pragma unroll
        for (int c = 0; c < 4; ++c) {
            float v[8];
            float4 q0 = *(const float4*)(px + c * 32);
            float4 q1 = *(const float4*)(px + c * 32 + 4);
            v[0]=q0.x; v[1]=q0.y; v[2]=q0.z; v[3]=q0.w; v[4]=q1.x; v[5]=q1.y; v[6]=q1.z; v[7]=q1.w;
            split8(v, xh[c], xl[c]);
        }
        f32x4 o0 = {be0, be0, be0, be0};
        f32x4 o1 = {be1, be1, be1, be1};
        f32x4 ca = {0.f, 0.f, 0.f, 0.f};
        #pragma unroll
        for (int c = 0; c < 4; ++c) {
            MF3(xh[c], xl[c], beh[c][0], bel[c][0], o0);
            MF3(xh[c], xl[c], beh[c][1], bel[c][1], o1);
            MF3(xh[c], xl[c], bah[c],    bal[c],    ca);
        }
        #pragma unroll
        for (int j = 0; j < 4; ++j) {
            int n = n0 + lg * 4 + j;
            if (n < N) {
                out[(size_t)n * DIM + f * ND + lr]       = o0[j];
                out[(size_t)n * DIM + f * ND + 16 + lr]  = o1[j];
                st16[(size_t)n * DIM + f * ND + lr]      = (unsigned short)f2bf(o0[j]);
                st16[(size_t)n * DIM + f * ND + 16 + lr] = (unsigned short)f2bf(o1[j]);
                if (lr == 0)      alr[(size_t)n * 8 + f]     = ca[j];
                else if (lr == 1) alr[(size_t)n * 8 + 4 + f] = ca[j];
            }
        }
    }
}

// ---------------- CSR build (scan3 folded into consumers) ----------------
__global__ void hist_kernel(const int* __restrict__ ei, int* __restrict__ deg) {
    int e = blockIdx.x * 256 + threadIdx.x;
    if (e < E) atomicAdd(&deg[ei[E + e]], 1);
}

__global__ void scan1_kernel(const int* __restrict__ deg, int* __restrict__ rowp,
                             int* __restrict__ bsum) {
    __shared__ int sh[256];
    int i = blockIdx.x * 256 + threadIdx.x;
    int v = (i < N) ? deg[i] : 0;
    sh[threadIdx.x] = v;
    __syncthreads();
    for (int off = 1; off < 256; off <<= 1) {
        int t = 0;
        if ((int)threadIdx.x >= off) t = sh[threadIdx.x - off];
        __syncthreads();
        sh[threadIdx.x] += t;
        __syncthreads();
    }
    if (i < N) rowp[i] = sh[threadIdx.x] - v;   // block-local exclusive prefix
    if (threadIdx.x == 255) bsum[blockIdx.x] = sh[255];
}

__global__ void scan2_kernel(int* __restrict__ bsum) {
    __shared__ int sh[256];
    int v = ((int)threadIdx.x < NB) ? bsum[threadIdx.x] : 0;
    sh[threadIdx.x] = v;
    __syncthreads();
    for (int off = 1; off < 256; off <<= 1) {
        int t = 0;
        if ((int)threadIdx.x >= off) t = sh[threadIdx.x - off];
        __syncthreads();
        sh[threadIdx.x] += t;
        __syncthreads();
    }
    if ((int)threadIdx.x < NB) bsum[threadIdx.x] = sh[threadIdx.x] - v;
}

// fill + attention fused. slot base = rowp[d] + bsum[d>>8] (scan3 folded in).
__global__ void fill_kernel(const int* __restrict__ ei, const float* __restrict__ alr,
                            const float* __restrict__ cc,
                            const int* __restrict__ rowp, const int* __restrict__ bsum,
                            int* __restrict__ cnt,
                            uint4* __restrict__ erec, float* __restrict__ atts) {
    int e = blockIdx.x * 256 + threadIdx.x;
    if (e >= E) return;
    int s = ei[e];
    int d = ei[E + e];
    float4 al = *(const float4*)(alr + (size_t)s * 8);
    float4 ar = *(const float4*)(alr + (size_t)d * 8 + 4);
    float a0 = sigm(6.f * (al.x + ar.x + cc[0]));
    float a1 = sigm(6.f * (al.y + ar.y + cc[1]));
    float a2 = sigm(6.f * (al.z + ar.z + cc[2]));
    float a3 = sigm(6.f * (al.w + ar.w + cc[3]));
    atts[e]                 = a0;
    atts[(size_t)E + e]     = a1;
    atts[2 * (size_t)E + e] = a2;
    atts[3 * (size_t)E + e] = a3;
    unsigned int p01 = (unsigned int)__half_as_ushort(__float2half(a0))
                     | ((unsigned int)__half_as_ushort(__float2half(a1)) << 16);
    unsigned int p23 = (unsigned int)__half_as_ushort(__float2half(a2))
                     | ((unsigned int)__half_as_ushort(__float2half(a3)) << 16);
    int slot = rowp[d] + bsum[d >> 8] + atomicAdd(&cnt[d], 1);
    erec[slot] = make_uint4((unsigned int)s, p01, p23, 0u);
}

// ---------------- gather: TWO nodes per wave (32 lanes / node, 4 ch / lane) ----------
// Doubles independent load streams per wave vs one-node-per-wave; per-channel fp32
// accumulation order unchanged -> bit-identical agghi/agglo.
__global__ __launch_bounds__(256) void gather_kernel(
        const uint4* __restrict__ erec,
        const int* __restrict__ rowp, const int* __restrict__ bsum,
        const int* __restrict__ deg,
        const unsigned short* __restrict__ st16,
        unsigned int* __restrict__ agghi, unsigned int* __restrict__ agglo) {
    int tid  = threadIdx.x;
    int lane = tid & 63;
    int half = lane >> 5;
    int l2   = lane & 31;
    int n = blockIdx.x * 8 + ((tid >> 6) << 1) + half;   // < N (N % 8 == 0)
    int beg = rowp[n] + bsum[n >> 8];
    int cnt = deg[n];
    const uint4* rp4 = erec + beg;
    int f = l2 >> 3;                      // channel group of ch 4*l2
    const int fhi = f >> 1;
    const int ash = (f & 1) * 16;
    const unsigned short* ob = st16 + 4 * l2;   // channels 4*l2 .. 4*l2+3 (8B/lane)
    float s0 = 0.f, s1 = 0.f, s2 = 0.f, s3 = 0.f;
    int i = 0;
    #define REXT(r) __half2float(__ushort_as_half((unsigned short)(((fhi ? (r).z : (r).y)) >> ash)))
    #define ROW(r)  (*(const uint2*)(ob + (size_t)(r).x * DIM))
    #define ACC(a, u) do { \
        s0 += (a) * __uint_as_float((u).x << 16); \
        s1 += (a) * __uint_as_float((u).x & 0xFFFF0000u); \
        s2 += (a) * __uint_as_float((u).y << 16); \
        s3 += (a) * __uint_as_float((u).y & 0xFFFF0000u); } while (0)
    for (; i + 8 <= cnt; i += 8) {
        uint4 r0 = rp4[i],     r1 = rp4[i + 1], r2 = rp4[i + 2], r3 = rp4[i + 3];
        uint4 r4 = rp4[i + 4], r5 = rp4[i + 5], r6 = rp4[i + 6], r7 = rp4[i + 7];
        uint2 u0 = ROW(r0), u1 = ROW(r1), u2 = ROW(r2), u3 = ROW(r3);
        uint2 u4 = ROW(r4), u5 = ROW(r5), u6 = ROW(r6), u7 = ROW(r7);
        float a0 = REXT(r0), a1 = REXT(r1), a2 = REXT(r2), a3 = REXT(r3);
        float a4 = REXT(r4), a5 = REXT(r5), a6 = REXT(r6), a7 = REXT(r7);
        ACC(a0, u0); ACC(a1, u1); ACC(a2, u2); ACC(a3, u3);
        ACC(a4, u4); ACC(a5, u5); ACC(a6, u6); ACC(a7, u7);
    }
    for (; i + 4 <= cnt; i += 4) {
        uint4 r0 = rp4[i], r1 = rp4[i + 1], r2 = rp4[i + 2], r3 = rp4[i + 3];
        uint2 u0 = ROW(r0), u1 = ROW(r1), u2 = ROW(r2), u3 = ROW(r3);
        float a0 = REXT(r0), a1 = REXT(r1), a2 = REXT(r2), a3 = REXT(r3);
        ACC(a0, u0); ACC(a1, u1); ACC(a2, u2); ACC(a3, u3);
    }
    for (; i < cnt; ++i) {
        uint4 r = rp4[i];
        uint2 u = ROW(r);
        float a = REXT(r);
        ACC(a, u);
    }
    #undef REXT
    #undef ROW
    #undef ACC
    unsigned int h0 = f2bf(s0), h1 = f2bf(s1), h2 = f2bf(s2), h3 = f2bf(s3);
    uint2 hi, lo;
    hi.x = h0 | (h1 << 16);
    hi.y = h2 | (h3 << 16);
    lo.x = f2bf(s0 - __uint_as_float(h0 << 16)) | (f2bf(s1 - __uint_as_float(h1 << 16)) << 16);
    lo.y = f2bf(s2 - __uint_as_float(h2 << 16)) | (f2bf(s3 - __uint_as_float(h3 << 16)) << 16);
    *(uint2*)(agghi + (size_t)n * 64 + 2 * l2) = hi;
    *(uint2*)(agglo + (size_t)n * 64 + 2 * l2) = lo;
}

// ---------------- conv + GRU via MFMA (split-bf16 ~= fp32 precision) ----------------
__global__ __launch_bounds__(256) void update_kernel(
        const unsigned int* __restrict__ agghi, const unsigned int* __restrict__ agglo,
        float* __restrict__ out, unsigned short* __restrict__ st16,
        const unsigned short* __restrict__ convfrag, const unsigned short* __restrict__ grufrag,
        const float* __restrict__ brel,
        const float* __restrict__ bih, const float* __restrict__ bhh, int lay) {
    __shared__ __align__(16) unsigned short mls[NF][2][2][16 * 40];  // [wave][subtile][hi/lo]
    int tid = threadIdx.x;
    int f   = __builtin_amdgcn_readfirstlane(tid >> 6);
    int l   = tid & 63;
    int lr  = l & 15;     // A-row / B-col / D-col
    int lg  = l >> 4;     // k-group / D row-group
    int node0 = blockIdx.x * 32;

    const unsigned short* cf = convfrag + (size_t)(f * NL + lay) * 8 * 64 * 8;
    s16x8 wrelh[2], wrell[2], wrooth[2], wrootl[2];
    #pragma unroll
    for (int H = 0; H < 2; ++H) {
        wrelh[H]  = *(const s16x8*)&cf[((0 + H) * 64 + l) * 8];
        wrell[H]  = *(const s16x8*)&cf[((2 + H) * 64 + l) * 8];
        wrooth[H] = *(const s16x8*)&cf[((4 + H) * 64 + l) * 8];
        wrootl[H] = *(const s16x8*)&cf[((6 + H) * 64 + l) * 8];
    }
    const unsigned short* gf = grufrag + (size_t)f * 6 * 4 * 64 * 8;
    s16x8 wirh[2], wirl[2], wizh[2], wizl[2], winh[2], winl[2];
    s16x8 whrh[2], whrl[2], whzh[2], whzl[2], whnh[2], whnl[2];
    #pragma unroll
    for (int H = 0; H < 2; ++H) {
        wirh[H] = *(const s16x8*)&gf[((0 * 4 + H) * 64 + l) * 8];
        wirl[H] = *(const s16x8*)&gf[((0 * 4 + 2 + H) * 64 + l) * 8];
        wizh[H] = *(const s16x8*)&gf[((1 * 4 + H) * 64 + l) * 8];
        wizl[H] = *(const s16x8*)&gf[((1 * 4 + 2 + H) * 64 + l) * 8];
        winh[H] = *(const s16x8*)&gf[((2 * 4 + H) * 64 + l) * 8];
        winl[H] = *(const s16x8*)&gf[((2 * 4 + 2 + H) * 64 + l) * 8];
        whrh[H] = *(const s16x8*)&gf[((3 * 4 + H) * 64 + l) * 8];
        whrl[H] = *(const s16x8*)&gf[((3 * 4 + 2 + H) * 64 + l) * 8];
        whzh[H] = *(const s16x8*)&gf[((4 * 4 + H) * 64 + l) * 8];
        whzl[H] = *(const s16x8*)&gf[((4 * 4 + 2 + H) * 64 + l) * 8];
        whnh[H] = *(const s16x8*)&gf[((5 * 4 + H) * 64 + l) * 8];
        whnl[H] = *(const s16x8*)&gf[((5 * 4 + 2 + H) * 64 + l) * 8];
    }

    float br_[2], bir_[2], biz_[2], bin_[2], bhn_[2];
    #pragma unroll
    for (int H = 0; H < 2; ++H) {
        int c = H * 16 + lr;
        br_[H]  = brel[(f * NL + lay) * 32 + c];
        bir_[H] = bih[f * 96 + c]      + bhh[f * 96 + c];
        biz_[H] = bih[f * 96 + 32 + c] + bhh[f * 96 + 32 + c];
        bin_[H] = bih[f * 96 + 64 + c];
        bhn_[H] = bhh[f * 96 + 64 + c];
    }

    const unsigned short* ahp = (const unsigned short*)agghi;
    const unsigned short* alp = (const unsigned short*)agglo;

    #pragma unroll
    for (int s = 0; s < 2; ++s) {
        int n0 = node0 + s * 16;
        unsigned short* mHi = &mls[f][s][0][0];
        unsigned short* mLo = &mls[f][s][1][0];
        int na  = n0 + lr;
        int nac = na < N ? na : N - 1;
        s16x8 aggH = *(const s16x8*)&ahp[(size_t)nac * DIM + f * ND + lg * 8];
        s16x8 aggL = *(const s16x8*)&alp[(size_t)nac * DIM + f * ND + lg * 8];
        const float* ph = out + (size_t)nac * DIM + f * ND + lg * 8;
        float vh[8];
        { float4 q0 = *(const float4*)ph, q1 = *(const float4*)(ph + 4);
          vh[0]=q0.x; vh[1]=q0.y; vh[2]=q0.z; vh[3]=q0.w; vh[4]=q1.x; vh[5]=q1.y; vh[6]=q1.z; vh[7]=q1.w; }
        s16x8 hH, hL;
        split8(vh, hH, hL);
        float hj0[4], hj1[4];
        #pragma unroll
        for (int j = 0; j < 4; ++j) {
            int nn_ = n0 + lg * 4 + j;
            int nnc = nn_ < N ? nn_ : N - 1;
            hj0[j] = out[(size_t)nnc * DIM + f * ND + lr];
            hj1[j] = out[(size_t)nnc * DIM + f * ND + 16 + lr];
        }

        f32x4 c0 = {br_[0], br_[0], br_[0], br_[0]};
        f32x4 c1 = {br_[1], br_[1], br_[1], br_[1]};
        MF3(aggH, aggL, wrelh[0],  wrell[0],  c0);
        MF3(hH,   hL,   wrooth[0], wrootl[0], c0);
        MF3(aggH, aggL, wrelh[1],  wrell[1],  c1);
        MF3(hH,   hL,   wrooth[1], wrootl[1], c1);

        #pragma unroll
        for (int j = 0; j < 4; ++j) {
            int row = lg * 4 + j;
            float v0 = fmaxf(c0[j], 0.f);
            float v1 = fmaxf(c1[j], 0.f);
            unsigned int h0 = f2bf(v0);
            unsigned int h1 = f2bf(v1);
            mHi[row * 40 + lr]      = (unsigned short)h0;
            mHi[row * 40 + 16 + lr] = (unsigned short)h1;
            mLo[row * 40 + lr]      = (unsigned short)f2bf(v0 - __uint_as_float(h0 << 16));
            mLo[row * 40 + 16 + lr] = (unsigned short)f2bf(v1 - __uint_as_float(h1 << 16));
        }
        __asm__ volatile("s_waitcnt lgkmcnt(0)" ::: "memory");   // wave-private buffer
        __builtin_amdgcn_sched_barrier(0x37);   // block DS+MFMA crossing; allow ALU/SALU/VMEM
        s16x8 mH = *(const s16x8*)&mHi[lr * 40 + lg * 8];
        s16x8 mL = *(const s16x8*)&mLo[lr * 40 + lg * 8];

        f32x4 gr0 = {bir_[0], bir_[0], bir_[0], bir_[0]};
        f32x4 gr1 = {bir_[1], bir_[1], bir_[1], bir_[1]};
        f32x4 gz0 = {biz_[0], biz_[0], biz_[0], biz_[0]};
        f32x4 gz1 = {biz_[1], biz_[1], biz_[1], biz_[1]};
        f32x4 gn0 = {bin_[0], bin_[0], bin_[0], bin_[0]};
        f32x4 gn1 = {bin_[1], bin_[1], bin_[1], bin_[1]};
        f32x4 gh0 = {bhn_[0], bhn_[0], bhn_[0], bhn_[0]};
        f32x4 gh1 = {bhn_[1], bhn_[1], bhn_[1], bhn_[1]};
        MF3(mH, mL, wirh[0], wirl[0], gr0);  MF3(hH, hL, whrh[0], whrl[0], gr0);
        MF3(mH, mL, wirh[1], wirl[1], gr1);  MF3(hH, hL, whrh[1], whrl[1], gr1);
        MF3(mH, mL, wizh[0], wizl[0], gz0);  MF3(hH, hL, whzh[0], whzl[0], gz0);
        MF3(mH, mL, wizh[1], wizl[1], gz1);  MF3(hH, hL, whzh[1], whzl[1], gz1);
        MF3(mH, mL, winh[0], winl[0], gn0);
        MF3(mH, mL, winh[1], winl[1], gn1);
        MF3(hH, hL, whnh[0], whnl[0], gh0);
        MF3(hH, hL, whnh[1], whnl[1], gh1);

        #pragma unroll
        for (int j = 0; j < 4; ++j) {
            int n = n0 + lg * 4 + j;
            float r0 = sigm(gr0[j]);
            float z0 = sigm(gz0[j]);
            float t0 = 2.f * sigm(2.f * (gn0[j] + r0 * gh0[j])) - 1.f;   // tanh
            float res0 = (1.f - z0) * t0 + z0 * hj0[j];
            float r1 = sigm(gr1[j]);
            float z1 = sigm(gz1[j]);
            float t1 = 2.f * sigm(2.f * (gn1[j] + r1 * gh1[j])) - 1.f;
            float res1 = (1.f - z1) * t1 + z1 * hj1[j];
            if (n < N) {
                out[(size_t)n * DIM + f * ND + lr]       = res0;
                out[(size_t)n * DIM + f * ND + 16 + lr]  = res1;
                st16[(size_t)n * DIM + f * ND + lr]      = (unsigned short)f2bf(res0);
                st16[(size_t)n * DIM + f * ND + 16 + lr] = (unsigned short)f2bf(res1);
            }
        }
    }
}

// ---------------- pooling + MLP fused (one block per group) ----------------
__global__ void poolmlp_kernel(const float* __restrict__ st, const int* __restrict__ goff,
                               const float* __restrict__ fc1_W, const float* __restrict__ fc1_b,
                               const float* __restrict__ fc2_W, const float* __restrict__ fc2_b,
                               float* __restrict__ pred, float* __restrict__ outsout) {
    __shared__ float acc2[DIM];
    __shared__ float row[DIM];
    __shared__ float hid[DIM];
    int g = blockIdx.x;
    int c = threadIdx.x & 127;
    int half = threadIdx.x >> 7;
    int beg = goff[g], cnt = goff[g + 1] - beg;
    float acc = 0.f;
    for (int i = half; i < cnt; i += 2) acc += st[(size_t)(beg + i) * DIM + c];
    if (half == 1) acc2[c] = acc;
    __syncthreads();
    if (half == 0) {
        float val = (acc + acc2[c]) / fmaxf((float)cnt, 1.0f);
        row[c] = val;
        int f = c >> 5, d = c & 31;
        outsout[((size_t)f * G + g) * ND + d] = val;
    }
    __syncthreads();
    if (half == 0) {
        float a = fc1_b[c];
        #pragma unroll 8
        for (int k = 0; k < DIM; ++k) a += row[k] * fc1_W[k * DIM + c];
        hid[c] = fmaxf(a, 0.f);
    }
    __syncthreads();
    if (threadIdx.x < NC) {
        float p = fc2_b[threadIdx.x];
        for (int k = 0; k < DIM; ++k) p += hid[k] * fc2_W[k * NC + threadIdx.x];
        pred[(size_t)g * NC + threadIdx.x] = p;
    }
}

extern "C" void kernel_launch(void* const* d_in, const int* in_sizes, int n_in,
                              void* d_out, int out_size, void* d_ws, size_t ws_size,
                              hipStream_t stream) {
    const float* x         = (const float*)d_in[0];
    const int*   ei        = (const int*)  d_in[1];
    const int*   batch     = (const int*)  d_in[2];
    const float* lin0_W    = (const float*)d_in[3];
    const float* lin0_b    = (const float*)d_in[4];
    const float* att_W     = (const float*)d_in[5];
    const float* att_b     = (const float*)d_in[6];
    const float* enc_W     = (const float*)d_in[7];
    const float* enc_b     = (const float*)d_in[8];
    const float* conv_Wrel = (const float*)d_in[9];
    const float* conv_brel = (const float*)d_in[10];
    const float* conv_Wroot= (const float*)d_in[11];
    const float* gru_Wih   = (const float*)d_in[12];
    const float* gru_Whh   = (const float*)d_in[13];
    const float* gru_bih   = (const float*)d_in[14];
    const float* gru_bhh   = (const float*)d_in[15];
    const float* fc1_W     = (const float*)d_in[16];
    const float* fc1_b     = (const float*)d_in[17];
    const float* fc2_W     = (const float*)d_in[18];
    const float* fc2_b     = (const float*)d_in[19];

    float* outp    = (float*)d_out;
    float* pred    = outp;                       // G*NC
    float* atts    = outp + G * NC;              // NF*E
    float* outsout = atts + (size_t)NF * E;      // NF*G*ND

    float* fp     = (float*)d_ws;
    float* st     = fp;                   fp += (size_t)N * DIM;
    unsigned int* agghi = (unsigned int*)fp;     fp += (size_t)N * 64;   // packed bf16-hi pairs
    unsigned int* agglo = (unsigned int*)fp;     fp += (size_t)N * 64;   // packed bf16-lo pairs
    unsigned short* st16 = (unsigned short*)fp;  fp += (size_t)N * DIM / 2;
    float* alr    = fp;                   fp += (size_t)N * 8;
    float* cc     = fp;                   fp += 4;
    unsigned short* convfrag = (unsigned short*)fp;  fp += 12 * 8 * 64 * 8 / 2;
    unsigned short* grufrag  = (unsigned short*)fp;  fp += 4 * 24 * 64 * 8 / 2;
    unsigned short* encfrag  = (unsigned short*)fp;  fp += 4 * 16 * 64 * 8 / 2;
    unsigned short* attfrag  = (unsigned short*)fp;  fp += 4 * 8 * 64 * 8 / 2;
    uint4* erec  = (uint4*)fp;            fp += (size_t)NF * E;   // 16B records, E of them
    int* ip    = (int*)fp;
    int* deg   = ip;                      ip += N;
    int* cnt   = ip;                      ip += N;   // deg & cnt adjacent -> one memset
    int* rowp  = ip;                      ip += N;
    int* bsum  = ip;                      ip += 256;
    int* goff  = ip;                      ip += G + 1;

    hipMemsetAsync(deg, 0, (size_t)(2 * N) * sizeof(int), stream);

    setup_kernel<<<22, 256, 0, stream>>>(lin0_W, lin0_b, att_W, att_b,
                                         conv_Wrel, conv_Wroot, gru_Wih, gru_Whh,
                                         enc_W, batch,
                                         convfrag, grufrag, encfrag, attfrag, cc, goff);
    encode_kernel<<<(N + 31) / 32, 256, 0, stream>>>(x, encfrag, attfrag, enc_b,
                                                     st, st16, alr);

    hist_kernel<<<(E + 255) / 256, 256, 0, stream>>>(ei, deg);
    scan1_kernel<<<NB, 256, 0, stream>>>(deg, rowp, bsum);
    scan2_kernel<<<1, 256, 0, stream>>>(bsum);
    fill_kernel<<<(E + 255) / 256, 256, 0, stream>>>(ei, alr, cc, rowp, bsum, cnt,
                                                     erec, atts);

    for (int l = 0; l < NL; ++l) {
        gather_kernel<<<N / 8, 256, 0, stream>>>(erec, rowp, bsum, deg, st16,
                                                 agghi, agglo);
        update_kernel<<<(N + 31) / 32, 256, 0, stream>>>(agghi, agglo, st, st16,
                                                         convfrag, grufrag, conv_brel,
                                                         gru_bih, gru_bhh, l);
    }

    poolmlp_kernel<<<G, 256, 0, stream>>>(st, goff, fc1_W, fc1_b, fc2_W, fc2_b,
                                          pred, outsout);
}

// Round 14
// 465.713 us; speedup vs baseline: 1.1218x; 1.1218x over previous
//
#include <hip/hip_runtime.h>
#include <hip/hip_fp16.h>
#include <math.h>

#define N   50000
#define E   800000
#define F   128
#define DIM 128
#define NF  4
#define ND  32
#define NL  3
#define NC  10
#define G   256
#define NB  196    // ceil(N/256) scan blocks

typedef __attribute__((ext_vector_type(8))) short  s16x8;   // 8 bf16 (4 VGPRs) MFMA operand
typedef __attribute__((ext_vector_type(4))) float  f32x4;   // MFMA accumulator

__device__ __forceinline__ float sigm(float v) { return 1.0f / (1.0f + __expf(-v)); }

__device__ __forceinline__ unsigned int f2bf(float x) {   // RNE round to bf16
    unsigned int u = __float_as_uint(x);
    return (u + 0x7FFFu + ((u >> 16) & 1u)) >> 16;
}

// split x into hi+lo bf16 pair (hi = bf16(x), lo = bf16(x - hi)): 3-term MFMA gives ~fp32
__device__ __forceinline__ void split8(const float* v, s16x8& hi, s16x8& lo) {
    #pragma unroll
    for (int i = 0; i < 8; ++i) {
        float x = v[i];
        unsigned int h = f2bf(x);
        float hf = __uint_as_float(h << 16);
        hi[i] = (short)h;
        lo[i] = (short)f2bf(x - hf);
    }
}

#define MFMA(a, b, c) c = __builtin_amdgcn_mfma_f32_16x16x32_bf16(a, b, c, 0, 0, 0)
// split product: (xh+xl)(wh+wl) ~= xh*wh + xh*wl + xl*wh
#define MF3(xh, xl, wh, wl, c) do { MFMA(xh, wh, c); MFMA(xh, wl, c); MFMA(xl, wh, c); } while (0)

// vl[f][k] = sum_j lin0_W[f][k][j]*att_W[f][j] ; vr likewise; cc = att_b + b.(Wl+Wr)
// (parallel: 512 threads, one (f,k) dot each -- round-13's inline version serialized
// this inside setup and cost ~95us)
__global__ void prep_kernel(const float* __restrict__ lin0_W, const float* __restrict__ lin0_b,
                            const float* __restrict__ att_W, const float* __restrict__ att_b,
                            float* __restrict__ vl, float* __restrict__ vr, float* __restrict__ cc) {
    int t = blockIdx.x * blockDim.x + threadIdx.x;
    if (t < NF * F) {
        int f = t >> 7, k = t & 127;
        const float* W  = lin0_W + (size_t)f * F * DIM + (size_t)k * DIM;
        const float* wl = att_W + f * 2 * DIM;
        const float* wr = wl + DIM;
        float sl = 0.f, sr = 0.f;
        for (int j = 0; j < DIM; ++j) { sl += W[j] * wl[j]; sr += W[j] * wr[j]; }
        vl[t] = sl; vr[t] = sr;
    }
    if (t < NF) {
        const float* b  = lin0_b + t * DIM;
        const float* wl = att_W + t * 2 * DIM;
        const float* wr = wl + DIM;
        float s = att_b[t];
        for (int j = 0; j < DIM; ++j) s += b[j] * (wl[j] + wr[j]);
        cc[t] = s;
    }
}

// ---------------- one-shot setup: weight fragments + goff ----------------
// blocks 0..11: conv frags (f*3+lay); 12..15: gru frags (f); 16..19: enc+att frags
// (att frags read precomputed vl/vr); 20: goff binary searches.
__global__ void setup_kernel(const float* __restrict__ Wrel, const float* __restrict__ Wroot,
                             const float* __restrict__ Wih, const float* __restrict__ Whh,
                             const float* __restrict__ enc_W,
                             const float* __restrict__ vl, const float* __restrict__ vr,
                             const int* __restrict__ batch,
                             unsigned short* __restrict__ convfrag,
                             unsigned short* __restrict__ grufrag,
                             unsigned short* __restrict__ encfrag,
                             unsigned short* __restrict__ attfrag,
                             int* __restrict__ goff) {
    int b = blockIdx.x;
    int tid = threadIdx.x;
    if (b < 20 && tid >= 64) return;
    int l = tid & 63;
    int lr = l & 15, lg = l >> 4;
    if (b < 12) {
        const float* wrelg  = Wrel  + (size_t)b * 1024;   // b == f*NL+lay
        const float* wrootg = Wroot + (size_t)b * 1024;
        #pragma unroll
        for (int H = 0; H < 2; ++H) {
            #pragma unroll
            for (int i = 0; i < 8; ++i) {
                float x = wrelg[(lg * 8 + i) * 32 + H * 16 + lr];
                unsigned int h = f2bf(x);
                convfrag[(((size_t)b * 8 + 0 + H) * 64 + l) * 8 + i] = (unsigned short)h;
                convfrag[(((size_t)b * 8 + 2 + H) * 64 + l) * 8 + i] =
                    (unsigned short)f2bf(x - __uint_as_float(h << 16));
                x = wrootg[(lg * 8 + i) * 32 + H * 16 + lr];
                h = f2bf(x);
                convfrag[(((size_t)b * 8 + 4 + H) * 64 + l) * 8 + i] = (unsigned short)h;
                convfrag[(((size_t)b * 8 + 6 + H) * 64 + l) * 8 + i] =
                    (unsigned short)f2bf(x - __uint_as_float(h << 16));
            }
        }
    } else if (b < 16) {
        int f = b - 12;
        const float* wihg = Wih + (size_t)f * 3072;   // [96][32] row-major
        const float* whhg = Whh + (size_t)f * 3072;
        #pragma unroll
        for (int m = 0; m < 6; ++m) {
            const float* base = (m < 3 ? wihg : whhg) + (size_t)((m % 3) * 32) * 32;
            #pragma unroll
            for (int H = 0; H < 2; ++H) {
                int col = H * 16 + lr;
                #pragma unroll
                for (int i = 0; i < 8; ++i) {
                    float x = base[(size_t)col * 32 + lg * 8 + i];
                    unsigned int h = f2bf(x);
                    grufrag[(((size_t)(f * 6 + m) * 4 + H) * 64 + l) * 8 + i] = (unsigned short)h;
                    grufrag[(((size_t)(f * 6 + m) * 4 + 2 + H) * 64 + l) * 8 + i] =
                        (unsigned short)f2bf(x - __uint_as_float(h << 16));
                }
            }
        }
    } else if (b < 20) {
        int f = b - 16;
        const float* we = enc_W + (size_t)f * F * ND;   // [128][32]
        #pragma unroll
        for (int c = 0; c < 4; ++c) {
            #pragma unroll
            for (int i = 0; i < 8; ++i) {
                int k = c * 32 + lg * 8 + i;
                #pragma unroll
                for (int H = 0; H < 2; ++H) {
                    float x = we[(size_t)k * 32 + H * 16 + lr];
                    unsigned int h = f2bf(x);
                    encfrag[((((size_t)(f * 4 + c) * 2 + H) * 2 + 0) * 64 + l) * 8 + i] =
                        (unsigned short)h;
                    encfrag[((((size_t)(f * 4 + c) * 2 + H) * 2 + 1) * 64 + l) * 8 + i] =
                        (unsigned short)f2bf(x - __uint_as_float(h << 16));
                }
                float av = (lr == 0) ? vl[f * F + k] : (lr == 1) ? vr[f * F + k] : 0.f;
                unsigned int ha = f2bf(av);
                attfrag[(((size_t)(f * 4 + c) * 2 + 0) * 64 + l) * 8 + i] = (unsigned short)ha;
                attfrag[(((size_t)(f * 4 + c) * 2 + 1) * 64 + l) * 8 + i] =
                    (unsigned short)f2bf(av - __uint_as_float(ha << 16));
            }
        }
    } else {
        int g = tid;   // 0..255: goff[g] = lower_bound(batch, g)
        int lo = 0, hi = N;
        while (lo < hi) {
            int mid = (lo + hi) >> 1;
            if (batch[mid] < g) lo = mid + 1; else hi = mid;
        }
        goff[g] = lo;
        if (g == 0) goff[G] = N;
    }
}

// ---------------- encode via MFMA (split-bf16 ~= fp32) ----------------
__global__ __launch_bounds__(256) void encode_kernel(
        const float* __restrict__ x,
        const unsigned short* __restrict__ encfrag,
        const unsigned short* __restrict__ attfrag,
        const float* __restrict__ enc_b,
        float* __restrict__ out, unsigned short* __restrict__ st16,
        float* __restrict__ alr) {
    int tid = threadIdx.x;
    int f  = __builtin_amdgcn_readfirstlane(tid >> 6);
    int l  = tid & 63;
    int lr = l & 15, lg = l >> 4;
    int node0 = blockIdx.x * 32;

    s16x8 beh[4][2], bel[4][2], bah[4], bal[4];
    #pragma unroll
    for (int c = 0; c < 4; ++c) {
        #pragma unroll
        for (int H = 0; H < 2; ++H) {
            beh[c][H] = *(const s16x8*)&encfrag[((((size_t)(f*4 + c)*2 + H)*2 + 0)*64 + l)*8];
            bel[c][H] = *(const s16x8*)&encfrag[((((size_t)(f*4 + c)*2 + H)*2 + 1)*64 + l)*8];
        }
        bah[c] = *(const s16x8*)&attfrag[(((size_t)(f*4 + c)*2 + 0)*64 + l)*8];
        bal[c] = *(const s16x8*)&attfrag[(((size_t)(f*4 + c)*2 + 1)*64 + l)*8];
    }
    float be0 = enc_b[f*32 + lr], be1 = enc_b[f*32 + 16 + lr];

    #pragma unroll
    for (int s = 0; s < 2; ++s) {
        int n0 = node0 + s * 16;
        int na = n0 + lr; int nac = na < N ? na : N - 1;
        const float* px = x + (size_t)nac * F + lg * 8;
        s16x8 xh[4], xl[4];
        #pragma unroll
        for (int c = 0; c < 4; ++c) {
            float v[8];
            float4 q0 = *(const float4*)(px + c * 32);
            float4 q1 = *(const float4*)(px + c * 32 + 4);
            v[0]=q0.x; v[1]=q0.y; v[2]=q0.z; v[3]=q0.w; v[4]=q1.x; v[5]=q1.y; v[6]=q1.z; v[7]=q1.w;
            split8(v, xh[c], xl[c]);
        }
        f32x4 o0 = {be0, be0, be0, be0};
        f32x4 o1 = {be1, be1, be1, be1};
        f32x4 ca = {0.f, 0.f, 0.f, 0.f};
        #pragma unroll
        for (int c = 0; c < 4; ++c) {
            MF3(xh[c], xl[c], beh[c][0], bel[c][0], o0);
            MF3(xh[c], xl[c], beh[c][1], bel[c][1], o1);
            MF3(xh[c], xl[c], bah[c],    bal[c],    ca);
        }
        #pragma unroll
        for (int j = 0; j < 4; ++j) {
            int n = n0 + lg * 4 + j;
            if (n < N) {
                out[(size_t)n * DIM + f * ND + lr]       = o0[j];
                out[(size_t)n * DIM + f * ND + 16 + lr]  = o1[j];
                st16[(size_t)n * DIM + f * ND + lr]      = (unsigned short)f2bf(o0[j]);
                st16[(size_t)n * DIM + f * ND + 16 + lr] = (unsigned short)f2bf(o1[j]);
                if (lr == 0)      alr[(size_t)n * 8 + f]     = ca[j];
                else if (lr == 1) alr[(size_t)n * 8 + 4 + f] = ca[j];
            }
        }
    }
}

// ---------------- CSR build (scan3 folded into consumers) ----------------
__global__ void hist_kernel(const int* __restrict__ ei, int* __restrict__ deg) {
    int e = blockIdx.x * 256 + threadIdx.x;
    if (e < E) atomicAdd(&deg[ei[E + e]], 1);
}

__global__ void scan1_kernel(const int* __restrict__ deg, int* __restrict__ rowp,
                             int* __restrict__ bsum) {
    __shared__ int sh[256];
    int i = blockIdx.x * 256 + threadIdx.x;
    int v = (i < N) ? deg[i] : 0;
    sh[threadIdx.x] = v;
    __syncthreads();
    for (int off = 1; off < 256; off <<= 1) {
        int t = 0;
        if ((int)threadIdx.x >= off) t = sh[threadIdx.x - off];
        __syncthreads();
        sh[threadIdx.x] += t;
        __syncthreads();
    }
    if (i < N) rowp[i] = sh[threadIdx.x] - v;   // block-local exclusive prefix
    if (threadIdx.x == 255) bsum[blockIdx.x] = sh[255];
}

__global__ void scan2_kernel(int* __restrict__ bsum) {
    __shared__ int sh[256];
    int v = ((int)threadIdx.x < NB) ? bsum[threadIdx.x] : 0;
    sh[threadIdx.x] = v;
    __syncthreads();
    for (int off = 1; off < 256; off <<= 1) {
        int t = 0;
        if ((int)threadIdx.x >= off) t = sh[threadIdx.x - off];
        __syncthreads();
        sh[threadIdx.x] += t;
        __syncthreads();
    }
    if ((int)threadIdx.x < NB) bsum[threadIdx.x] = sh[threadIdx.x] - v;
}

// fill + attention fused. slot base = rowp[d] + bsum[d>>8] (scan3 folded in).
__global__ void fill_kernel(const int* __restrict__ ei, const float* __restrict__ alr,
                            const float* __restrict__ cc,
                            const int* __restrict__ rowp, const int* __restrict__ bsum,
                            int* __restrict__ cnt,
                            uint4* __restrict__ erec, float* __restrict__ atts) {
    int e = blockIdx.x * 256 + threadIdx.x;
    if (e >= E) return;
    int s = ei[e];
    int d = ei[E + e];
    float4 al = *(const float4*)(alr + (size_t)s * 8);
    float4 ar = *(const float4*)(alr + (size_t)d * 8 + 4);
    float a0 = sigm(6.f * (al.x + ar.x + cc[0]));
    float a1 = sigm(6.f * (al.y + ar.y + cc[1]));
    float a2 = sigm(6.f * (al.z + ar.z + cc[2]));
    float a3 = sigm(6.f * (al.w + ar.w + cc[3]));
    atts[e]                 = a0;
    atts[(size_t)E + e]     = a1;
    atts[2 * (size_t)E + e] = a2;
    atts[3 * (size_t)E + e] = a3;
    unsigned int p01 = (unsigned int)__half_as_ushort(__float2half(a0))
                     | ((unsigned int)__half_as_ushort(__float2half(a1)) << 16);
    unsigned int p23 = (unsigned int)__half_as_ushort(__float2half(a2))
                     | ((unsigned int)__half_as_ushort(__float2half(a3)) << 16);
    int slot = rowp[d] + bsum[d >> 8] + atomicAdd(&cnt[d], 1);
    erec[slot] = make_uint4((unsigned int)s, p01, p23, 0u);
}

// ---------------- gather: TWO nodes per wave (32 lanes / node, 4 ch / lane) ----------
__global__ __launch_bounds__(256) void gather_kernel(
        const uint4* __restrict__ erec,
        const int* __restrict__ rowp, const int* __restrict__ bsum,
        const int* __restrict__ deg,
        const unsigned short* __restrict__ st16,
        unsigned int* __restrict__ agghi, unsigned int* __restrict__ agglo) {
    int tid  = threadIdx.x;
    int lane = tid & 63;
    int half = lane >> 5;
    int l2   = lane & 31;
    int n = blockIdx.x * 8 + ((tid >> 6) << 1) + half;   // < N (N % 8 == 0)
    int beg = rowp[n] + bsum[n >> 8];
    int cnt = deg[n];
    const uint4* rp4 = erec + beg;
    int f = l2 >> 3;                      // channel group of ch 4*l2
    const int fhi = f >> 1;
    const int ash = (f & 1) * 16;
    const unsigned short* ob = st16 + 4 * l2;   // channels 4*l2 .. 4*l2+3 (8B/lane)
    float s0 = 0.f, s1 = 0.f, s2 = 0.f, s3 = 0.f;
    int i = 0;
    #define REXT(r) __half2float(__ushort_as_half((unsigned short)(((fhi ? (r).z : (r).y)) >> ash)))
    #define ROW(r)  (*(const uint2*)(ob + (size_t)(r).x * DIM))
    #define ACC(a, u) do { \
        s0 += (a) * __uint_as_float((u).x << 16); \
        s1 += (a) * __uint_as_float((u).x & 0xFFFF0000u); \
        s2 += (a) * __uint_as_float((u).y << 16); \
        s3 += (a) * __uint_as_float((u).y & 0xFFFF0000u); } while (0)
    for (; i + 8 <= cnt; i += 8) {
        uint4 r0 = rp4[i],     r1 = rp4[i + 1], r2 = rp4[i + 2], r3 = rp4[i + 3];
        uint4 r4 = rp4[i + 4], r5 = rp4[i + 5], r6 = rp4[i + 6], r7 = rp4[i + 7];
        uint2 u0 = ROW(r0), u1 = ROW(r1), u2 = ROW(r2), u3 = ROW(r3);
        uint2 u4 = ROW(r4), u5 = ROW(r5), u6 = ROW(r6), u7 = ROW(r7);
        float a0 = REXT(r0), a1 = REXT(r1), a2 = REXT(r2), a3 = REXT(r3);
        float a4 = REXT(r4), a5 = REXT(r5), a6 = REXT(r6), a7 = REXT(r7);
        ACC(a0, u0); ACC(a1, u1); ACC(a2, u2); ACC(a3, u3);
        ACC(a4, u4); ACC(a5, u5); ACC(a6, u6); ACC(a7, u7);
    }
    for (; i + 4 <= cnt; i += 4) {
        uint4 r0 = rp4[i], r1 = rp4[i + 1], r2 = rp4[i + 2], r3 = rp4[i + 3];
        uint2 u0 = ROW(r0), u1 = ROW(r1), u2 = ROW(r2), u3 = ROW(r3);
        float a0 = REXT(r0), a1 = REXT(r1), a2 = REXT(r2), a3 = REXT(r3);
        ACC(a0, u0); ACC(a1, u1); ACC(a2, u2); ACC(a3, u3);
    }
    for (; i < cnt; ++i) {
        uint4 r = rp4[i];
        uint2 u = ROW(r);
        float a = REXT(r);
        ACC(a, u);
    }
    #undef REXT
    #undef ROW
    #undef ACC
    unsigned int h0 = f2bf(s0), h1 = f2bf(s1), h2 = f2bf(s2), h3 = f2bf(s3);
    uint2 hi, lo;
    hi.x = h0 | (h1 << 16);
    hi.y = h2 | (h3 << 16);
    lo.x = f2bf(s0 - __uint_as_float(h0 << 16)) | (f2bf(s1 - __uint_as_float(h1 << 16)) << 16);
    lo.y = f2bf(s2 - __uint_as_float(h2 << 16)) | (f2bf(s3 - __uint_as_float(h3 << 16)) << 16);
    *(uint2*)(agghi + (size_t)n * 64 + 2 * l2) = hi;
    *(uint2*)(agglo + (size_t)n * 64 + 2 * l2) = lo;
}

// ---------------- conv + GRU via MFMA (split-bf16 ~= fp32 precision) ----------------
__global__ __launch_bounds__(256) void update_kernel(
        const unsigned int* __restrict__ agghi, const unsigned int* __restrict__ agglo,
        float* __restrict__ out, unsigned short* __restrict__ st16,
        const unsigned short* __restrict__ convfrag, const unsigned short* __restrict__ grufrag,
        const float* __restrict__ brel,
        const float* __restrict__ bih, const float* __restrict__ bhh, int lay) {
    __shared__ __align__(16) unsigned short mls[NF][2][2][16 * 40];  // [wave][subtile][hi/lo]
    int tid = threadIdx.x;
    int f   = __builtin_amdgcn_readfirstlane(tid >> 6);
    int l   = tid & 63;
    int lr  = l & 15;     // A-row / B-col / D-col
    int lg  = l >> 4;     // k-group / D row-group
    int node0 = blockIdx.x * 32;

    const unsigned short* cf = convfrag + (size_t)(f * NL + lay) * 8 * 64 * 8;
    s16x8 wrelh[2], wrell[2], wrooth[2], wrootl[2];
    #pragma unroll
    for (int H = 0; H < 2; ++H) {
        wrelh[H]  = *(const s16x8*)&cf[((0 + H) * 64 + l) * 8];
        wrell[H]  = *(const s16x8*)&cf[((2 + H) * 64 + l) * 8];
        wrooth[H] = *(const s16x8*)&cf[((4 + H) * 64 + l) * 8];
        wrootl[H] = *(const s16x8*)&cf[((6 + H) * 64 + l) * 8];
    }
    const unsigned short* gf = grufrag + (size_t)f * 6 * 4 * 64 * 8;
    s16x8 wirh[2], wirl[2], wizh[2], wizl[2], winh[2], winl[2];
    s16x8 whrh[2], whrl[2], whzh[2], whzl[2], whnh[2], whnl[2];
    #pragma unroll
    for (int H = 0; H < 2; ++H) {
        wirh[H] = *(const s16x8*)&gf[((0 * 4 + H) * 64 + l) * 8];
        wirl[H] = *(const s16x8*)&gf[((0 * 4 + 2 + H) * 64 + l) * 8];
        wizh[H] = *(const s16x8*)&gf[((1 * 4 + H) * 64 + l) * 8];
        wizl[H] = *(const s16x8*)&gf[((1 * 4 + 2 + H) * 64 + l) * 8];
        winh[H] = *(const s16x8*)&gf[((2 * 4 + H) * 64 + l) * 8];
        winl[H] = *(const s16x8*)&gf[((2 * 4 + 2 + H) * 64 + l) * 8];
        whrh[H] = *(const s16x8*)&gf[((3 * 4 + H) * 64 + l) * 8];
        whrl[H] = *(const s16x8*)&gf[((3 * 4 + 2 + H) * 64 + l) * 8];
        whzh[H] = *(const s16x8*)&gf[((4 * 4 + H) * 64 + l) * 8];
        whzl[H] = *(const s16x8*)&gf[((4 * 4 + 2 + H) * 64 + l) * 8];
        whnh[H] = *(const s16x8*)&gf[((5 * 4 + H) * 64 + l) * 8];
        whnl[H] = *(const s16x8*)&gf[((5 * 4 + 2 + H) * 64 + l) * 8];
    }

    float br_[2], bir_[2], biz_[2], bin_[2], bhn_[2];
    #pragma unroll
    for (int H = 0; H < 2; ++H) {
        int c = H * 16 + lr;
        br_[H]  = brel[(f * NL + lay) * 32 + c];
        bir_[H] = bih[f * 96 + c]      + bhh[f * 96 + c];
        biz_[H] = bih[f * 96 + 32 + c] + bhh[f * 96 + 32 + c];
        bin_[H] = bih[f * 96 + 64 + c];
        bhn_[H] = bhh[f * 96 + 64 + c];
    }

    const unsigned short* ahp = (const unsigned short*)agghi;
    const unsigned short* alp = (const unsigned short*)agglo;

    #pragma unroll
    for (int s = 0; s < 2; ++s) {
        int n0 = node0 + s * 16;
        unsigned short* mHi = &mls[f][s][0][0];
        unsigned short* mLo = &mls[f][s][1][0];
        int na  = n0 + lr;
        int nac = na < N ? na : N - 1;
        s16x8 aggH = *(const s16x8*)&ahp[(size_t)nac * DIM + f * ND + lg * 8];
        s16x8 aggL = *(const s16x8*)&alp[(size_t)nac * DIM + f * ND + lg * 8];
        const float* ph = out + (size_t)nac * DIM + f * ND + lg * 8;
        float vh[8];
        { float4 q0 = *(const float4*)ph, q1 = *(const float4*)(ph + 4);
          vh[0]=q0.x; vh[1]=q0.y; vh[2]=q0.z; vh[3]=q0.w; vh[4]=q1.x; vh[5]=q1.y; vh[6]=q1.z; vh[7]=q1.w; }
        s16x8 hH, hL;
        split8(vh, hH, hL);
        float hj0[4], hj1[4];
        #pragma unroll
        for (int j = 0; j < 4; ++j) {
            int nn_ = n0 + lg * 4 + j;
            int nnc = nn_ < N ? nn_ : N - 1;
            hj0[j] = out[(size_t)nnc * DIM + f * ND + lr];
            hj1[j] = out[(size_t)nnc * DIM + f * ND + 16 + lr];
        }

        f32x4 c0 = {br_[0], br_[0], br_[0], br_[0]};
        f32x4 c1 = {br_[1], br_[1], br_[1], br_[1]};
        MF3(aggH, aggL, wrelh[0],  wrell[0],  c0);
        MF3(hH,   hL,   wrooth[0], wrootl[0], c0);
        MF3(aggH, aggL, wrelh[1],  wrell[1],  c1);
        MF3(hH,   hL,   wrooth[1], wrootl[1], c1);

        #pragma unroll
        for (int j = 0; j < 4; ++j) {
            int row = lg * 4 + j;
            float v0 = fmaxf(c0[j], 0.f);
            float v1 = fmaxf(c1[j], 0.f);
            unsigned int h0 = f2bf(v0);
            unsigned int h1 = f2bf(v1);
            mHi[row * 40 + lr]      = (unsigned short)h0;
            mHi[row * 40 + 16 + lr] = (unsigned short)h1;
            mLo[row * 40 + lr]      = (unsigned short)f2bf(v0 - __uint_as_float(h0 << 16));
            mLo[row * 40 + 16 + lr] = (unsigned short)f2bf(v1 - __uint_as_float(h1 << 16));
        }
        __asm__ volatile("s_waitcnt lgkmcnt(0)" ::: "memory");   // wave-private buffer
        __builtin_amdgcn_sched_barrier(0x37);   // block DS+MFMA crossing; allow ALU/SALU/VMEM
        s16x8 mH = *(const s16x8*)&mHi[lr * 40 + lg * 8];
        s16x8 mL = *(const s16x8*)&mLo[lr * 40 + lg * 8];

        f32x4 gr0 = {bir_[0], bir_[0], bir_[0], bir_[0]};
        f32x4 gr1 = {bir_[1], bir_[1], bir_[1], bir_[1]};
        f32x4 gz0 = {biz_[0], biz_[0], biz_[0], biz_[0]};
        f32x4 gz1 = {biz_[1], biz_[1], biz_[1], biz_[1]};
        f32x4 gn0 = {bin_[0], bin_[0], bin_[0], bin_[0]};
        f32x4 gn1 = {bin_[1], bin_[1], bin_[1], bin_[1]};
        f32x4 gh0 = {bhn_[0], bhn_[0], bhn_[0], bhn_[0]};
        f32x4 gh1 = {bhn_[1], bhn_[1], bhn_[1], bhn_[1]};
        MF3(mH, mL, wirh[0], wirl[0], gr0);  MF3(hH, hL, whrh[0], whrl[0], gr0);
        MF3(mH, mL, wirh[1], wirl[1], gr1);  MF3(hH, hL, whrh[1], whrl[1], gr1);
        MF3(mH, mL, wizh[0], wizl[0], gz0);  MF3(hH, hL, whzh[0], whzl[0], gz0);
        MF3(mH, mL, wizh[1], wizl[1], gz1);  MF3(hH, hL, whzh[1], whzl[1], gz1);
        MF3(mH, mL, winh[0], winl[0], gn0);
        MF3(mH, mL, winh[1], winl[1], gn1);
        MF3(hH, hL, whnh[0], whnl[0], gh0);
        MF3(hH, hL, whnh[1], whnl[1], gh1);

        #pragma unroll
        for (int j = 0; j < 4; ++j) {
            int n = n0 + lg * 4 + j;
            float r0 = sigm(gr0[j]);
            float z0 = sigm(gz0[j]);
            float t0 = 2.f * sigm(2.f * (gn0[j] + r0 * gh0[j])) - 1.f;   // tanh
            float res0 = (1.f - z0) * t0 + z0 * hj0[j];
            float r1 = sigm(gr1[j]);
            float z1 = sigm(gz1[j]);
            float t1 = 2.f * sigm(2.f * (gn1[j] + r1 * gh1[j])) - 1.f;
            float res1 = (1.f - z1) * t1 + z1 * hj1[j];
            if (n < N) {
                out[(size_t)n * DIM + f * ND + lr]       = res0;
                out[(size_t)n * DIM + f * ND + 16 + lr]  = res1;
                st16[(size_t)n * DIM + f * ND + lr]      = (unsigned short)f2bf(res0);
                st16[(size_t)n * DIM + f * ND + 16 + lr] = (unsigned short)f2bf(res1);
            }
        }
    }
}

// ---------------- pooling + MLP fused (one block per group) ----------------
__global__ void poolmlp_kernel(const float* __restrict__ st, const int* __restrict__ goff,
                               const float* __restrict__ fc1_W, const float* __restrict__ fc1_b,
                               const float* __restrict__ fc2_W, const float* __restrict__ fc2_b,
                               float* __restrict__ pred, float* __restrict__ outsout) {
    __shared__ float acc2[DIM];
    __shared__ float row[DIM];
    __shared__ float hid[DIM];
    int g = blockIdx.x;
    int c = threadIdx.x & 127;
    int half = threadIdx.x >> 7;
    int beg = goff[g], cnt = goff[g + 1] - beg;
    float acc = 0.f;
    for (int i = half; i < cnt; i += 2) acc += st[(size_t)(beg + i) * DIM + c];
    if (half == 1) acc2[c] = acc;
    __syncthreads();
    if (half == 0) {
        float val = (acc + acc2[c]) / fmaxf((float)cnt, 1.0f);
        row[c] = val;
        int f = c >> 5, d = c & 31;
        outsout[((size_t)f * G + g) * ND + d] = val;
    }
    __syncthreads();
    if (half == 0) {
        float a = fc1_b[c];
        #pragma unroll 8
        for (int k = 0; k < DIM; ++k) a += row[k] * fc1_W[k * DIM + c];
        hid[c] = fmaxf(a, 0.f);
    }
    __syncthreads();
    if (threadIdx.x < NC) {
        float p = fc2_b[threadIdx.x];
        for (int k = 0; k < DIM; ++k) p += hid[k] * fc2_W[k * NC + threadIdx.x];
        pred[(size_t)g * NC + threadIdx.x] = p;
    }
}

extern "C" void kernel_launch(void* const* d_in, const int* in_sizes, int n_in,
                              void* d_out, int out_size, void* d_ws, size_t ws_size,
                              hipStream_t stream) {
    const float* x         = (const float*)d_in[0];
    const int*   ei        = (const int*)  d_in[1];
    const int*   batch     = (const int*)  d_in[2];
    const float* lin0_W    = (const float*)d_in[3];
    const float* lin0_b    = (const float*)d_in[4];
    const float* att_W     = (const float*)d_in[5];
    const float* att_b     = (const float*)d_in[6];
    const float* enc_W     = (const float*)d_in[7];
    const float* enc_b     = (const float*)d_in[8];
    const float* conv_Wrel = (const float*)d_in[9];
    const float* conv_brel = (const float*)d_in[10];
    const float* conv_Wroot= (const float*)d_in[11];
    const float* gru_Wih   = (const float*)d_in[12];
    const float* gru_Whh   = (const float*)d_in[13];
    const float* gru_bih   = (const float*)d_in[14];
    const float* gru_bhh   = (const float*)d_in[15];
    const float* fc1_W     = (const float*)d_in[16];
    const float* fc1_b     = (const float*)d_in[17];
    const float* fc2_W     = (const float*)d_in[18];
    const float* fc2_b     = (const float*)d_in[19];

    float* outp    = (float*)d_out;
    float* pred    = outp;                       // G*NC
    float* atts    = outp + G * NC;              // NF*E
    float* outsout = atts + (size_t)NF * E;      // NF*G*ND

    float* fp     = (float*)d_ws;
    float* st     = fp;                   fp += (size_t)N * DIM;
    unsigned int* agghi = (unsigned int*)fp;     fp += (size_t)N * 64;   // packed bf16-hi pairs
    unsigned int* agglo = (unsigned int*)fp;     fp += (size_t)N * 64;   // packed bf16-lo pairs
    unsigned short* st16 = (unsigned short*)fp;  fp += (size_t)N * DIM / 2;
    float* alr    = fp;                   fp += (size_t)N * 8;
    float* vl     = fp;                   fp += NF * F;
    float* vr     = fp;                   fp += NF * F;
    float* cc     = fp;                   fp += 4;
    unsigned short* convfrag = (unsigned short*)fp;  fp += 12 * 8 * 64 * 8 / 2;
    unsigned short* grufrag  = (unsigned short*)fp;  fp += 4 * 24 * 64 * 8 / 2;
    unsigned short* encfrag  = (unsigned short*)fp;  fp += 4 * 16 * 64 * 8 / 2;
    unsigned short* attfrag  = (unsigned short*)fp;  fp += 4 * 8 * 64 * 8 / 2;
    uint4* erec  = (uint4*)fp;            fp += (size_t)NF * E;   // 16B records, E of them
    int* ip    = (int*)fp;
    int* deg   = ip;                      ip += N;
    int* cnt   = ip;                      ip += N;   // deg & cnt adjacent -> one memset
    int* rowp  = ip;                      ip += N;
    int* bsum  = ip;                      ip += 256;
    int* goff  = ip;                      ip += G + 1;

    hipMemsetAsync(deg, 0, (size_t)(2 * N) * sizeof(int), stream);

    prep_kernel<<<2, 256, 0, stream>>>(lin0_W, lin0_b, att_W, att_b, vl, vr, cc);
    setup_kernel<<<21, 256, 0, stream>>>(conv_Wrel, conv_Wroot, gru_Wih, gru_Whh,
                                         enc_W, vl, vr, batch,
                                         convfrag, grufrag, encfrag, attfrag, goff);
    encode_kernel<<<(N + 31) / 32, 256, 0, stream>>>(x, encfrag, attfrag, enc_b,
                                                     st, st16, alr);

    hist_kernel<<<(E + 255) / 256, 256, 0, stream>>>(ei, deg);
    scan1_kernel<<<NB, 256, 0, stream>>>(deg, rowp, bsum);
    scan2_kernel<<<1, 256, 0, stream>>>(bsum);
    fill_kernel<<<(E + 255) / 256, 256, 0, stream>>>(ei, alr, cc, rowp, bsum, cnt,
                                                     erec, atts);

    for (int l = 0; l < NL; ++l) {
        gather_kernel<<<N / 8, 256, 0, stream>>>(erec, rowp, bsum, deg, st16,
                                                 agghi, agglo);
        update_kernel<<<(N + 31) / 32, 256, 0, stream>>>(agghi, agglo, st, st16,
                                                         convfrag, grufrag, conv_brel,
                                                         gru_bih, gru_bhh, l);
    }

    poolmlp_kernel<<<G, 256, 0, stream>>>(st, goff, fc1_W, fc1_b, fc2_W, fc2_b,
                                          pred, outsout);
}

// Round 15
// 447.846 us; speedup vs baseline: 1.1665x; 1.0399x over previous
//
#include <hip/hip_runtime.h>
#include <hip/hip_fp16.h>
#include <math.h>

#define N   50000
#define E   800000
#define F   128
#define DIM 128
#define NF  4
#define ND  32
#define NL  3
#define NC  10
#define G   256
#define NB  196    // ceil(N/256) scan blocks

typedef __attribute__((ext_vector_type(8))) short  s16x8;   // 8 bf16 (4 VGPRs) MFMA operand
typedef __attribute__((ext_vector_type(4))) float  f32x4;   // MFMA accumulator

__device__ __forceinline__ float sigm(float v) { return 1.0f / (1.0f + __expf(-v)); }

__device__ __forceinline__ unsigned int f2bf(float x) {   // RNE round to bf16
    unsigned int u = __float_as_uint(x);
    return (u + 0x7FFFu + ((u >> 16) & 1u)) >> 16;
}

// split x into hi+lo bf16 pair (hi = bf16(x), lo = bf16(x - hi)): 3-term MFMA gives ~fp32
__device__ __forceinline__ void split8(const float* v, s16x8& hi, s16x8& lo) {
    #pragma unroll
    for (int i = 0; i < 8; ++i) {
        float x = v[i];
        unsigned int h = f2bf(x);
        float hf = __uint_as_float(h << 16);
        hi[i] = (short)h;
        lo[i] = (short)f2bf(x - hf);
    }
}

#define MFMA(a, b, c) c = __builtin_amdgcn_mfma_f32_16x16x32_bf16(a, b, c, 0, 0, 0)
// split product: (xh+xl)(wh+wl) ~= xh*wh + xh*wl + xl*wh
#define MF3(xh, xl, wh, wl, c) do { MFMA(xh, wh, c); MFMA(xh, wl, c); MFMA(xl, wh, c); } while (0)

// vl[f][k] = sum_j lin0_W[f][k][j]*att_W[f][j] ; vr likewise; cc = att_b + b.(Wl+Wr)
__global__ void prep_kernel(const float* __restrict__ lin0_W, const float* __restrict__ lin0_b,
                            const float* __restrict__ att_W, const float* __restrict__ att_b,
                            float* __restrict__ vl, float* __restrict__ vr, float* __restrict__ cc) {
    int t = blockIdx.x * blockDim.x + threadIdx.x;
    if (t < NF * F) {
        int f = t >> 7, k = t & 127;
        const float* W  = lin0_W + (size_t)f * F * DIM + (size_t)k * DIM;
        const float* wl = att_W + f * 2 * DIM;
        const float* wr = wl + DIM;
        float sl = 0.f, sr = 0.f;
        for (int j = 0; j < DIM; ++j) { sl += W[j] * wl[j]; sr += W[j] * wr[j]; }
        vl[t] = sl; vr[t] = sr;
    }
    if (t < NF) {
        const float* b  = lin0_b + t * DIM;
        const float* wl = att_W + t * 2 * DIM;
        const float* wr = wl + DIM;
        float s = att_b[t];
        for (int j = 0; j < DIM; ++j) s += b[j] * (wl[j] + wr[j]);
        cc[t] = s;
    }
}

// ---------------- one-shot setup: weight fragments + goff ----------------
__global__ void setup_kernel(const float* __restrict__ Wrel, const float* __restrict__ Wroot,
                             const float* __restrict__ Wih, const float* __restrict__ Whh,
                             const float* __restrict__ enc_W,
                             const float* __restrict__ vl, const float* __restrict__ vr,
                             const int* __restrict__ batch,
                             unsigned short* __restrict__ convfrag,
                             unsigned short* __restrict__ grufrag,
                             unsigned short* __restrict__ encfrag,
                             unsigned short* __restrict__ attfrag,
                             int* __restrict__ goff) {
    int b = blockIdx.x;
    int tid = threadIdx.x;
    if (b < 20 && tid >= 64) return;
    int l = tid & 63;
    int lr = l & 15, lg = l >> 4;
    if (b < 12) {
        const float* wrelg  = Wrel  + (size_t)b * 1024;   // b == f*NL+lay
        const float* wrootg = Wroot + (size_t)b * 1024;
        #pragma unroll
        for (int H = 0; H < 2; ++H) {
            #pragma unroll
            for (int i = 0; i < 8; ++i) {
                float x = wrelg[(lg * 8 + i) * 32 + H * 16 + lr];
                unsigned int h = f2bf(x);
                convfrag[(((size_t)b * 8 + 0 + H) * 64 + l) * 8 + i] = (unsigned short)h;
                convfrag[(((size_t)b * 8 + 2 + H) * 64 + l) * 8 + i] =
                    (unsigned short)f2bf(x - __uint_as_float(h << 16));
                x = wrootg[(lg * 8 + i) * 32 + H * 16 + lr];
                h = f2bf(x);
                convfrag[(((size_t)b * 8 + 4 + H) * 64 + l) * 8 + i] = (unsigned short)h;
                convfrag[(((size_t)b * 8 + 6 + H) * 64 + l) * 8 + i] =
                    (unsigned short)f2bf(x - __uint_as_float(h << 16));
            }
        }
    } else if (b < 16) {
        int f = b - 12;
        const float* wihg = Wih + (size_t)f * 3072;   // [96][32] row-major
        const float* whhg = Whh + (size_t)f * 3072;
        #pragma unroll
        for (int m = 0; m < 6; ++m) {
            const float* base = (m < 3 ? wihg : whhg) + (size_t)((m % 3) * 32) * 32;
            #pragma unroll
            for (int H = 0; H < 2; ++H) {
                int col = H * 16 + lr;
                #pragma unroll
                for (int i = 0; i < 8; ++i) {
                    float x = base[(size_t)col * 32 + lg * 8 + i];
                    unsigned int h = f2bf(x);
                    grufrag[(((size_t)(f * 6 + m) * 4 + H) * 64 + l) * 8 + i] = (unsigned short)h;
                    grufrag[(((size_t)(f * 6 + m) * 4 + 2 + H) * 64 + l) * 8 + i] =
                        (unsigned short)f2bf(x - __uint_as_float(h << 16));
                }
            }
        }
    } else if (b < 20) {
        int f = b - 16;
        const float* we = enc_W + (size_t)f * F * ND;   // [128][32]
        #pragma unroll
        for (int c = 0; c < 4; ++c) {
            #pragma unroll
            for (int i = 0; i < 8; ++i) {
                int k = c * 32 + lg * 8 + i;
                #pragma unroll
                for (int H = 0; H < 2; ++H) {
                    float x = we[(size_t)k * 32 + H * 16 + lr];
                    unsigned int h = f2bf(x);
                    encfrag[((((size_t)(f * 4 + c) * 2 + H) * 2 + 0) * 64 + l) * 8 + i] =
                        (unsigned short)h;
                    encfrag[((((size_t)(f * 4 + c) * 2 + H) * 2 + 1) * 64 + l) * 8 + i] =
                        (unsigned short)f2bf(x - __uint_as_float(h << 16));
                }
                float av = (lr == 0) ? vl[f * F + k] : (lr == 1) ? vr[f * F + k] : 0.f;
                unsigned int ha = f2bf(av);
                attfrag[(((size_t)(f * 4 + c) * 2 + 0) * 64 + l) * 8 + i] = (unsigned short)ha;
                attfrag[(((size_t)(f * 4 + c) * 2 + 1) * 64 + l) * 8 + i] =
                    (unsigned short)f2bf(av - __uint_as_float(ha << 16));
            }
        }
    } else {
        int g = tid;   // 0..255: goff[g] = lower_bound(batch, g)
        int lo = 0, hi = N;
        while (lo < hi) {
            int mid = (lo + hi) >> 1;
            if (batch[mid] < g) lo = mid + 1; else hi = mid;
        }
        goff[g] = lo;
        if (g == 0) goff[G] = N;
    }
}

// ---------------- encode via MFMA (split-bf16 ~= fp32) ----------------
__global__ __launch_bounds__(256) void encode_kernel(
        const float* __restrict__ x,
        const unsigned short* __restrict__ encfrag,
        const unsigned short* __restrict__ attfrag,
        const float* __restrict__ enc_b,
        float* __restrict__ out, unsigned short* __restrict__ st16,
        float* __restrict__ alr) {
    int tid = threadIdx.x;
    int f  = __builtin_amdgcn_readfirstlane(tid >> 6);
    int l  = tid & 63;
    int lr = l & 15, lg = l >> 4;
    int node0 = blockIdx.x * 32;

    s16x8 beh[4][2], bel[4][2], bah[4], bal[4];
    #pragma unroll
    for (int c = 0; c < 4; ++c) {
        #pragma unroll
        for (int H = 0; H < 2; ++H) {
            beh[c][H] = *(const s16x8*)&encfrag[((((size_t)(f*4 + c)*2 + H)*2 + 0)*64 + l)*8];
            bel[c][H] = *(const s16x8*)&encfrag[((((size_t)(f*4 + c)*2 + H)*2 + 1)*64 + l)*8];
        }
        bah[c] = *(const s16x8*)&attfrag[(((size_t)(f*4 + c)*2 + 0)*64 + l)*8];
        bal[c] = *(const s16x8*)&attfrag[(((size_t)(f*4 + c)*2 + 1)*64 + l)*8];
    }
    float be0 = enc_b[f*32 + lr], be1 = enc_b[f*32 + 16 + lr];

    #pragma unroll
    for (int s = 0; s < 2; ++s) {
        int n0 = node0 + s * 16;
        int na = n0 + lr; int nac = na < N ? na : N - 1;
        const float* px = x + (size_t)nac * F + lg * 8;
        s16x8 xh[4], xl[4];
        #pragma unroll
        for (int c = 0; c < 4; ++c) {
            float v[8];
            float4 q0 = *(const float4*)(px + c * 32);
            float4 q1 = *(const float4*)(px + c * 32 + 4);
            v[0]=q0.x; v[1]=q0.y; v[2]=q0.z; v[3]=q0.w; v[4]=q1.x; v[5]=q1.y; v[6]=q1.z; v[7]=q1.w;
            split8(v, xh[c], xl[c]);
        }
        f32x4 o0 = {be0, be0, be0, be0};
        f32x4 o1 = {be1, be1, be1, be1};
        f32x4 ca = {0.f, 0.f, 0.f, 0.f};
        #pragma unroll
        for (int c = 0; c < 4; ++c) {
            MF3(xh[c], xl[c], beh[c][0], bel[c][0], o0);
            MF3(xh[c], xl[c], beh[c][1], bel[c][1], o1);
            MF3(xh[c], xl[c], bah[c],    bal[c],    ca);
        }
        #pragma unroll
        for (int j = 0; j < 4; ++j) {
            int n = n0 + lg * 4 + j;
            if (n < N) {
                out[(size_t)n * DIM + f * ND + lr]       = o0[j];
                out[(size_t)n * DIM + f * ND + 16 + lr]  = o1[j];
                st16[(size_t)n * DIM + f * ND + lr]      = (unsigned short)f2bf(o0[j]);
                st16[(size_t)n * DIM + f * ND + 16 + lr] = (unsigned short)f2bf(o1[j]);
                if (lr == 0)      alr[(size_t)n * 8 + f]     = ca[j];
                else if (lr == 1) alr[(size_t)n * 8 + 4 + f] = ca[j];
            }
        }
    }
}

// ---------------- CSR build ----------------
// hist also records each edge's within-node index (the atomicAdd return it was
// discarding) -> fill needs NO atomic.
__global__ void hist_kernel(const int* __restrict__ ei, int* __restrict__ deg,
                            int* __restrict__ widx) {
    int e = blockIdx.x * 256 + threadIdx.x;
    if (e < E) widx[e] = atomicAdd(&deg[ei[E + e]], 1);
}

__global__ void scan1_kernel(const int* __restrict__ deg, int* __restrict__ rowp,
                             int* __restrict__ bsum) {
    __shared__ int sh[256];
    int i = blockIdx.x * 256 + threadIdx.x;
    int v = (i < N) ? deg[i] : 0;
    sh[threadIdx.x] = v;
    __syncthreads();
    for (int off = 1; off < 256; off <<= 1) {
        int t = 0;
        if ((int)threadIdx.x >= off) t = sh[threadIdx.x - off];
        __syncthreads();
        sh[threadIdx.x] += t;
        __syncthreads();
    }
    if (i < N) rowp[i] = sh[threadIdx.x] - v;   // block-local exclusive prefix
    if (threadIdx.x == 255) bsum[blockIdx.x] = sh[255];
}

__global__ void scan2_kernel(int* __restrict__ bsum) {
    __shared__ int sh[256];
    int v = ((int)threadIdx.x < NB) ? bsum[threadIdx.x] : 0;
    sh[threadIdx.x] = v;
    __syncthreads();
    for (int off = 1; off < 256; off <<= 1) {
        int t = 0;
        if ((int)threadIdx.x >= off) t = sh[threadIdx.x - off];
        __syncthreads();
        sh[threadIdx.x] += t;
        __syncthreads();
    }
    if ((int)threadIdx.x < NB) bsum[threadIdx.x] = sh[threadIdx.x] - v;
}

// fill + attention fused, ATOMIC-FREE: slot = rowp[d] + bsum[d>>8] + widx[e].
__global__ void fill_kernel(const int* __restrict__ ei, const float* __restrict__ alr,
                            const float* __restrict__ cc,
                            const int* __restrict__ rowp, const int* __restrict__ bsum,
                            const int* __restrict__ widx,
                            uint4* __restrict__ erec, float* __restrict__ atts) {
    int e = blockIdx.x * 256 + threadIdx.x;
    if (e >= E) return;
    int s = ei[e];
    int d = ei[E + e];
    float4 al = *(const float4*)(alr + (size_t)s * 8);
    float4 ar = *(const float4*)(alr + (size_t)d * 8 + 4);
    float a0 = sigm(6.f * (al.x + ar.x + cc[0]));
    float a1 = sigm(6.f * (al.y + ar.y + cc[1]));
    float a2 = sigm(6.f * (al.z + ar.z + cc[2]));
    float a3 = sigm(6.f * (al.w + ar.w + cc[3]));
    atts[e]                 = a0;
    atts[(size_t)E + e]     = a1;
    atts[2 * (size_t)E + e] = a2;
    atts[3 * (size_t)E + e] = a3;
    unsigned int p01 = (unsigned int)__half_as_ushort(__float2half(a0))
                     | ((unsigned int)__half_as_ushort(__float2half(a1)) << 16);
    unsigned int p23 = (unsigned int)__half_as_ushort(__float2half(a2))
                     | ((unsigned int)__half_as_ushort(__float2half(a3)) << 16);
    int slot = rowp[d] + bsum[d >> 8] + widx[e];
    erec[slot] = make_uint4((unsigned int)s, p01, p23, 0u);
}

// ---------------- gather: TWO nodes per wave (32 lanes / node, 4 ch / lane) ----------
__global__ __launch_bounds__(256) void gather_kernel(
        const uint4* __restrict__ erec,
        const int* __restrict__ rowp, const int* __restrict__ bsum,
        const int* __restrict__ deg,
        const unsigned short* __restrict__ st16,
        unsigned int* __restrict__ agghi, unsigned int* __restrict__ agglo) {
    int tid  = threadIdx.x;
    int lane = tid & 63;
    int half = lane >> 5;
    int l2   = lane & 31;
    int n = blockIdx.x * 8 + ((tid >> 6) << 1) + half;   // < N (N % 8 == 0)
    int beg = rowp[n] + bsum[n >> 8];
    int cnt = deg[n];
    const uint4* rp4 = erec + beg;
    int f = l2 >> 3;                      // channel group of ch 4*l2
    const int fhi = f >> 1;
    const int ash = (f & 1) * 16;
    const unsigned short* ob = st16 + 4 * l2;   // channels 4*l2 .. 4*l2+3 (8B/lane)
    float s0 = 0.f, s1 = 0.f, s2 = 0.f, s3 = 0.f;
    int i = 0;
    #define REXT(r) __half2float(__ushort_as_half((unsigned short)(((fhi ? (r).z : (r).y)) >> ash)))
    #define ROW(r)  (*(const uint2*)(ob + (size_t)(r).x * DIM))
    #define ACC(a, u) do { \
        s0 += (a) * __uint_as_float((u).x << 16); \
        s1 += (a) * __uint_as_float((u).x & 0xFFFF0000u); \
        s2 += (a) * __uint_as_float((u).y << 16); \
        s3 += (a) * __uint_as_float((u).y & 0xFFFF0000u); } while (0)
    for (; i + 8 <= cnt; i += 8) {
        uint4 r0 = rp4[i],     r1 = rp4[i + 1], r2 = rp4[i + 2], r3 = rp4[i + 3];
        uint4 r4 = rp4[i + 4], r5 = rp4[i + 5], r6 = rp4[i + 6], r7 = rp4[i + 7];
        uint2 u0 = ROW(r0), u1 = ROW(r1), u2 = ROW(r2), u3 = ROW(r3);
        uint2 u4 = ROW(r4), u5 = ROW(r5), u6 = ROW(r6), u7 = ROW(r7);
        float a0 = REXT(r0), a1 = REXT(r1), a2 = REXT(r2), a3 = REXT(r3);
        float a4 = REXT(r4), a5 = REXT(r5), a6 = REXT(r6), a7 = REXT(r7);
        ACC(a0, u0); ACC(a1, u1); ACC(a2, u2); ACC(a3, u3);
        ACC(a4, u4); ACC(a5, u5); ACC(a6, u6); ACC(a7, u7);
    }
    for (; i + 4 <= cnt; i += 4) {
        uint4 r0 = rp4[i], r1 = rp4[i + 1], r2 = rp4[i + 2], r3 = rp4[i + 3];
        uint2 u0 = ROW(r0), u1 = ROW(r1), u2 = ROW(r2), u3 = ROW(r3);
        float a0 = REXT(r0), a1 = REXT(r1), a2 = REXT(r2), a3 = REXT(r3);
        ACC(a0, u0); ACC(a1, u1); ACC(a2, u2); ACC(a3, u3);
    }
    for (; i < cnt; ++i) {
        uint4 r = rp4[i];
        uint2 u = ROW(r);
        float a = REXT(r);
        ACC(a, u);
    }
    #undef REXT
    #undef ROW
    #undef ACC
    unsigned int h0 = f2bf(s0), h1 = f2bf(s1), h2 = f2bf(s2), h3 = f2bf(s3);
    uint2 hi, lo;
    hi.x = h0 | (h1 << 16);
    hi.y = h2 | (h3 << 16);
    lo.x = f2bf(s0 - __uint_as_float(h0 << 16)) | (f2bf(s1 - __uint_as_float(h1 << 16)) << 16);
    lo.y = f2bf(s2 - __uint_as_float(h2 << 16)) | (f2bf(s3 - __uint_as_float(h3 << 16)) << 16);
    *(uint2*)(agghi + (size_t)n * 64 + 2 * l2) = hi;
    *(uint2*)(agglo + (size_t)n * 64 + 2 * l2) = lo;
}

// ---------------- conv + GRU via MFMA (split-bf16 ~= fp32 precision) ----------------
__global__ __launch_bounds__(256) void update_kernel(
        const unsigned int* __restrict__ agghi, const unsigned int* __restrict__ agglo,
        float* __restrict__ out, unsigned short* __restrict__ st16,
        const unsigned short* __restrict__ convfrag, const unsigned short* __restrict__ grufrag,
        const float* __restrict__ brel,
        const float* __restrict__ bih, const float* __restrict__ bhh, int lay) {
    __shared__ __align__(16) unsigned short mls[NF][2][2][16 * 40];  // [wave][subtile][hi/lo]
    int tid = threadIdx.x;
    int f   = __builtin_amdgcn_readfirstlane(tid >> 6);
    int l   = tid & 63;
    int lr  = l & 15;     // A-row / B-col / D-col
    int lg  = l >> 4;     // k-group / D row-group
    int node0 = blockIdx.x * 32;

    const unsigned short* cf = convfrag + (size_t)(f * NL + lay) * 8 * 64 * 8;
    s16x8 wrelh[2], wrell[2], wrooth[2], wrootl[2];
    #pragma unroll
    for (int H = 0; H < 2; ++H) {
        wrelh[H]  = *(const s16x8*)&cf[((0 + H) * 64 + l) * 8];
        wrell[H]  = *(const s16x8*)&cf[((2 + H) * 64 + l) * 8];
        wrooth[H] = *(const s16x8*)&cf[((4 + H) * 64 + l) * 8];
        wrootl[H] = *(const s16x8*)&cf[((6 + H) * 64 + l) * 8];
    }
    const unsigned short* gf = grufrag + (size_t)f * 6 * 4 * 64 * 8;
    s16x8 wirh[2], wirl[2], wizh[2], wizl[2], winh[2], winl[2];
    s16x8 whrh[2], whrl[2], whzh[2], whzl[2], whnh[2], whnl[2];
    #pragma unroll
    for (int H = 0; H < 2; ++H) {
        wirh[H] = *(const s16x8*)&gf[((0 * 4 + H) * 64 + l) * 8];
        wirl[H] = *(const s16x8*)&gf[((0 * 4 + 2 + H) * 64 + l) * 8];
        wizh[H] = *(const s16x8*)&gf[((1 * 4 + H) * 64 + l) * 8];
        wizl[H] = *(const s16x8*)&gf[((1 * 4 + 2 + H) * 64 + l) * 8];
        winh[H] = *(const s16x8*)&gf[((2 * 4 + H) * 64 + l) * 8];
        winl[H] = *(const s16x8*)&gf[((2 * 4 + 2 + H) * 64 + l) * 8];
        whrh[H] = *(const s16x8*)&gf[((3 * 4 + H) * 64 + l) * 8];
        whrl[H] = *(const s16x8*)&gf[((3 * 4 + 2 + H) * 64 + l) * 8];
        whzh[H] = *(const s16x8*)&gf[((4 * 4 + H) * 64 + l) * 8];
        whzl[H] = *(const s16x8*)&gf[((4 * 4 + 2 + H) * 64 + l) * 8];
        whnh[H] = *(const s16x8*)&gf[((5 * 4 + H) * 64 + l) * 8];
        whnl[H] = *(const s16x8*)&gf[((5 * 4 + 2 + H) * 64 + l) * 8];
    }

    float br_[2], bir_[2], biz_[2], bin_[2], bhn_[2];
    #pragma unroll
    for (int H = 0; H < 2; ++H) {
        int c = H * 16 + lr;
        br_[H]  = brel[(f * NL + lay) * 32 + c];
        bir_[H] = bih[f * 96 + c]      + bhh[f * 96 + c];
        biz_[H] = bih[f * 96 + 32 + c] + bhh[f * 96 + 32 + c];
        bin_[H] = bih[f * 96 + 64 + c];
        bhn_[H] = bhh[f * 96 + 64 + c];
    }

    const unsigned short* ahp = (const unsigned short*)agghi;
    const unsigned short* alp = (const unsigned short*)agglo;

    #pragma unroll
    for (int s = 0; s < 2; ++s) {
        int n0 = node0 + s * 16;
        unsigned short* mHi = &mls[f][s][0][0];
        unsigned short* mLo = &mls[f][s][1][0];
        int na  = n0 + lr;
        int nac = na < N ? na : N - 1;
        s16x8 aggH = *(const s16x8*)&ahp[(size_t)nac * DIM + f * ND + lg * 8];
        s16x8 aggL = *(const s16x8*)&alp[(size_t)nac * DIM + f * ND + lg * 8];
        const float* ph = out + (size_t)nac * DIM + f * ND + lg * 8;
        float vh[8];
        { float4 q0 = *(const float4*)ph, q1 = *(const float4*)(ph + 4);
          vh[0]=q0.x; vh[1]=q0.y; vh[2]=q0.z; vh[3]=q0.w; vh[4]=q1.x; vh[5]=q1.y; vh[6]=q1.z; vh[7]=q1.w; }
        s16x8 hH, hL;
        split8(vh, hH, hL);
        float hj0[4], hj1[4];
        #pragma unroll
        for (int j = 0; j < 4; ++j) {
            int nn_ = n0 + lg * 4 + j;
            int nnc = nn_ < N ? nn_ : N - 1;
            hj0[j] = out[(size_t)nnc * DIM + f * ND + lr];
            hj1[j] = out[(size_t)nnc * DIM + f * ND + 16 + lr];
        }

        f32x4 c0 = {br_[0], br_[0], br_[0], br_[0]};
        f32x4 c1 = {br_[1], br_[1], br_[1], br_[1]};
        MF3(aggH, aggL, wrelh[0],  wrell[0],  c0);
        MF3(hH,   hL,   wrooth[0], wrootl[0], c0);
        MF3(aggH, aggL, wrelh[1],  wrell[1],  c1);
        MF3(hH,   hL,   wrooth[1], wrootl[1], c1);

        #pragma unroll
        for (int j = 0; j < 4; ++j) {
            int row = lg * 4 + j;
            float v0 = fmaxf(c0[j], 0.f);
            float v1 = fmaxf(c1[j], 0.f);
            unsigned int h0 = f2bf(v0);
            unsigned int h1 = f2bf(v1);
            mHi[row * 40 + lr]      = (unsigned short)h0;
            mHi[row * 40 + 16 + lr] = (unsigned short)h1;
            mLo[row * 40 + lr]      = (unsigned short)f2bf(v0 - __uint_as_float(h0 << 16));
            mLo[row * 40 + 16 + lr] = (unsigned short)f2bf(v1 - __uint_as_float(h1 << 16));
        }
        __asm__ volatile("s_waitcnt lgkmcnt(0)" ::: "memory");   // wave-private buffer
        __builtin_amdgcn_sched_barrier(0x37);   // block DS+MFMA crossing; allow ALU/SALU/VMEM
        s16x8 mH = *(const s16x8*)&mHi[lr * 40 + lg * 8];
        s16x8 mL = *(const s16x8*)&mLo[lr * 40 + lg * 8];

        f32x4 gr0 = {bir_[0], bir_[0], bir_[0], bir_[0]};
        f32x4 gr1 = {bir_[1], bir_[1], bir_[1], bir_[1]};
        f32x4 gz0 = {biz_[0], biz_[0], biz_[0], biz_[0]};
        f32x4 gz1 = {biz_[1], biz_[1], biz_[1], biz_[1]};
        f32x4 gn0 = {bin_[0], bin_[0], bin_[0], bin_[0]};
        f32x4 gn1 = {bin_[1], bin_[1], bin_[1], bin_[1]};
        f32x4 gh0 = {bhn_[0], bhn_[0], bhn_[0], bhn_[0]};
        f32x4 gh1 = {bhn_[1], bhn_[1], bhn_[1], bhn_[1]};
        MF3(mH, mL, wirh[0], wirl[0], gr0);  MF3(hH, hL, whrh[0], whrl[0], gr0);
        MF3(mH, mL, wirh[1], wirl[1], gr1);  MF3(hH, hL, whrh[1], whrl[1], gr1);
        MF3(mH, mL, wizh[0], wizl[0], gz0);  MF3(hH, hL, whzh[0], whzl[0], gz0);
        MF3(mH, mL, wizh[1], wizl[1], gz1);  MF3(hH, hL, whzh[1], whzl[1], gz1);
        MF3(mH, mL, winh[0], winl[0], gn0);
        MF3(mH, mL, winh[1], winl[1], gn1);
        MF3(hH, hL, whnh[0], whnl[0], gh0);
        MF3(hH, hL, whnh[1], whnl[1], gh1);

        #pragma unroll
        for (int j = 0; j < 4; ++j) {
            int n = n0 + lg * 4 + j;
            float r0 = sigm(gr0[j]);
            float z0 = sigm(gz0[j]);
            float t0 = 2.f * sigm(2.f * (gn0[j] + r0 * gh0[j])) - 1.f;   // tanh
            float res0 = (1.f - z0) * t0 + z0 * hj0[j];
            float r1 = sigm(gr1[j]);
            float z1 = sigm(gz1[j]);
            float t1 = 2.f * sigm(2.f * (gn1[j] + r1 * gh1[j])) - 1.f;
            float res1 = (1.f - z1) * t1 + z1 * hj1[j];
            if (n < N) {
                out[(size_t)n * DIM + f * ND + lr]       = res0;
                out[(size_t)n * DIM + f * ND + 16 + lr]  = res1;
                st16[(size_t)n * DIM + f * ND + lr]      = (unsigned short)f2bf(res0);
                st16[(size_t)n * DIM + f * ND + 16 + lr] = (unsigned short)f2bf(res1);
            }
        }
    }
}

// ---------------- pooling + MLP fused (one block per group) ----------------
__global__ void poolmlp_kernel(const float* __restrict__ st, const int* __restrict__ goff,
                               const float* __restrict__ fc1_W, const float* __restrict__ fc1_b,
                               const float* __restrict__ fc2_W, const float* __restrict__ fc2_b,
                               float* __restrict__ pred, float* __restrict__ outsout) {
    __shared__ float acc2[DIM];
    __shared__ float row[DIM];
    __shared__ float hid[DIM];
    int g = blockIdx.x;
    int c = threadIdx.x & 127;
    int half = threadIdx.x >> 7;
    int beg = goff[g], cnt = goff[g + 1] - beg;
    float acc = 0.f;
    for (int i = half; i < cnt; i += 2) acc += st[(size_t)(beg + i) * DIM + c];
    if (half == 1) acc2[c] = acc;
    __syncthreads();
    if (half == 0) {
        float val = (acc + acc2[c]) / fmaxf((float)cnt, 1.0f);
        row[c] = val;
        int f = c >> 5, d = c & 31;
        outsout[((size_t)f * G + g) * ND + d] = val;
    }
    __syncthreads();
    if (half == 0) {
        float a = fc1_b[c];
        #pragma unroll 8
        for (int k = 0; k < DIM; ++k) a += row[k] * fc1_W[k * DIM + c];
        hid[c] = fmaxf(a, 0.f);
    }
    __syncthreads();
    if (threadIdx.x < NC) {
        float p = fc2_b[threadIdx.x];
        for (int k = 0; k < DIM; ++k) p += hid[k] * fc2_W[k * NC + threadIdx.x];
        pred[(size_t)g * NC + threadIdx.x] = p;
    }
}

extern "C" void kernel_launch(void* const* d_in, const int* in_sizes, int n_in,
                              void* d_out, int out_size, void* d_ws, size_t ws_size,
                              hipStream_t stream) {
    const float* x         = (const float*)d_in[0];
    const int*   ei        = (const int*)  d_in[1];
    const int*   batch     = (const int*)  d_in[2];
    const float* lin0_W    = (const float*)d_in[3];
    const float* lin0_b    = (const float*)d_in[4];
    const float* att_W     = (const float*)d_in[5];
    const float* att_b     = (const float*)d_in[6];
    const float* enc_W     = (const float*)d_in[7];
    const float* enc_b     = (const float*)d_in[8];
    const float* conv_Wrel = (const float*)d_in[9];
    const float* conv_brel = (const float*)d_in[10];
    const float* conv_Wroot= (const float*)d_in[11];
    const float* gru_Wih   = (const float*)d_in[12];
    const float* gru_Whh   = (const float*)d_in[13];
    const float* gru_bih   = (const float*)d_in[14];
    const float* gru_bhh   = (const float*)d_in[15];
    const float* fc1_W     = (const float*)d_in[16];
    const float* fc1_b     = (const float*)d_in[17];
    const float* fc2_W     = (const float*)d_in[18];
    const float* fc2_b     = (const float*)d_in[19];

    float* outp    = (float*)d_out;
    float* pred    = outp;                       // G*NC
    float* atts    = outp + G * NC;              // NF*E
    float* outsout = atts + (size_t)NF * E;      // NF*G*ND

    float* fp     = (float*)d_ws;
    float* st     = fp;                   fp += (size_t)N * DIM;
    unsigned int* agghi = (unsigned int*)fp;     fp += (size_t)N * 64;   // packed bf16-hi pairs
    unsigned int* agglo = (unsigned int*)fp;     fp += (size_t)N * 64;   // packed bf16-lo pairs
    unsigned short* st16 = (unsigned short*)fp;  fp += (size_t)N * DIM / 2;
    float* alr    = fp;                   fp += (size_t)N * 8;
    float* vl     = fp;                   fp += NF * F;
    float* vr     = fp;                   fp += NF * F;
    float* cc     = fp;                   fp += 4;
    unsigned short* convfrag = (unsigned short*)fp;  fp += 12 * 8 * 64 * 8 / 2;
    unsigned short* grufrag  = (unsigned short*)fp;  fp += 4 * 24 * 64 * 8 / 2;
    unsigned short* encfrag  = (unsigned short*)fp;  fp += 4 * 16 * 64 * 8 / 2;
    unsigned short* attfrag  = (unsigned short*)fp;  fp += 4 * 8 * 64 * 8 / 2;
    uint4* erec  = (uint4*)fp;            fp += (size_t)NF * E;   // 16B records, E of them
    int* ip    = (int*)fp;
    int* deg   = ip;                      ip += N;
    int* rowp  = ip;                      ip += N;
    int* bsum  = ip;                      ip += 256;
    int* goff  = ip;                      ip += G + 1;
    int* widx  = ip;                      ip += E;   // within-node edge index from hist

    hipMemsetAsync(deg, 0, (size_t)N * sizeof(int), stream);

    prep_kernel<<<2, 256, 0, stream>>>(lin0_W, lin0_b, att_W, att_b, vl, vr, cc);
    setup_kernel<<<21, 256, 0, stream>>>(conv_Wrel, conv_Wroot, gru_Wih, gru_Whh,
                                         enc_W, vl, vr, batch,
                                         convfrag, grufrag, encfrag, attfrag, goff);
    encode_kernel<<<(N + 31) / 32, 256, 0, stream>>>(x, encfrag, attfrag, enc_b,
                                                     st, st16, alr);

    hist_kernel<<<(E + 255) / 256, 256, 0, stream>>>(ei, deg, widx);
    scan1_kernel<<<NB, 256, 0, stream>>>(deg, rowp, bsum);
    scan2_kernel<<<1, 256, 0, stream>>>(bsum);
    fill_kernel<<<(E + 255) / 256, 256, 0, stream>>>(ei, alr, cc, rowp, bsum, widx,
                                                     erec, atts);

    for (int l = 0; l < NL; ++l) {
        gather_kernel<<<N / 8, 256, 0, stream>>>(erec, rowp, bsum, deg, st16,
                                                 agghi, agglo);
        update_kernel<<<(N + 31) / 32, 256, 0, stream>>>(agghi, agglo, st, st16,
                                                         convfrag, grufrag, conv_brel,
                                                         gru_bih, gru_bhh, l);
    }

    poolmlp_kernel<<<G, 256, 0, stream>>>(st, goff, fc1_W, fc1_b, fc2_W, fc2_b,
                                          pred, outsout);
}